// Round 7
// baseline (965.993 us; speedup 1.0000x reference)
//
#include <hip/hip_runtime.h>
#include <hip/hip_fp16.h>
#include <math.h>

#define NB   256
#define NT   512
#define NN   256
#define LL   256
#define HH   512
#define MLPHv 2048
#define INCv 8
#define NCOLS 150

typedef _Float16 f16x8 __attribute__((ext_vector_type(8)));
typedef float    f32x4 __attribute__((ext_vector_type(4)));
typedef unsigned short ushort_t;

// ---------------------------------------------------------------------------
// fp32 -> fp16 hi/lo split:  a ≈ hi + lo/4096, |residual| <= 2^-22 |a|.
// ---------------------------------------------------------------------------
__device__ __forceinline__ void split1(float f, ushort_t& h, ushort_t& l)
{
    __half hh = __float2half_rn(f);
    h = __half_as_ushort(hh);
    l = __half_as_ushort(__float2half_rn((f - __half2float(hh)) * 4096.f));
}

__device__ __forceinline__ void pack8(const float* fv, uint4& hv, uint4& lv)
{
    ushort_t h[8], l[8];
#pragma unroll
    for (int j = 0; j < 8; ++j) split1(fv[j], h[j], l[j]);
    hv.x = (unsigned)h[0] | ((unsigned)h[1] << 16);
    hv.y = (unsigned)h[2] | ((unsigned)h[3] << 16);
    hv.z = (unsigned)h[4] | ((unsigned)h[5] << 16);
    hv.w = (unsigned)h[6] | ((unsigned)h[7] << 16);
    lv.x = (unsigned)l[0] | ((unsigned)l[1] << 16);
    lv.y = (unsigned)l[2] | ((unsigned)l[3] << 16);
    lv.z = (unsigned)l[4] | ((unsigned)l[5] << 16);
    lv.w = (unsigned)l[6] | ((unsigned)l[7] << 16);
}

// ---------------------------------------------------------------------------
// Hierarchical device-scope grid barrier. bar[0..7]=sub counters,
// bar[8]=master, bar[9]=generation. Reset by host memset each launch.
// All 256 blocks co-resident (1 block/CU) by construction.
// ---------------------------------------------------------------------------
__device__ __forceinline__ void gsync(unsigned* bar, int bid)
{
    __threadfence();                 // release my block's writes (device scope)
    __syncthreads();
    if (threadIdx.x == 0) {
        unsigned* gen = bar + 9;
        unsigned g = __hip_atomic_load(gen, __ATOMIC_ACQUIRE, __HIP_MEMORY_SCOPE_AGENT);
        unsigned a = __hip_atomic_fetch_add(&bar[bid & 7], 1u, __ATOMIC_ACQ_REL, __HIP_MEMORY_SCOPE_AGENT);
        if (a == 31u) {
            unsigned m = __hip_atomic_fetch_add(&bar[8], 1u, __ATOMIC_ACQ_REL, __HIP_MEMORY_SCOPE_AGENT);
            if (m == 7u) {
#pragma unroll
                for (int i = 0; i < 9; ++i)
                    __hip_atomic_store(&bar[i], 0u, __ATOMIC_RELAXED, __HIP_MEMORY_SCOPE_AGENT);
                __hip_atomic_fetch_add(gen, 1u, __ATOMIC_RELEASE, __HIP_MEMORY_SCOPE_AGENT);
            } else {
                while (__hip_atomic_load(gen, __ATOMIC_ACQUIRE, __HIP_MEMORY_SCOPE_AGENT) == g)
                    __builtin_amdgcn_s_sleep(2);
            }
        } else {
            while (__hip_atomic_load(gen, __ATOMIC_ACQUIRE, __HIP_MEMORY_SCOPE_AGENT) == g)
                __builtin_amdgcn_s_sleep(2);
        }
    }
    __syncthreads();
    __threadfence();                 // acquire: no stale reads of others' data
}

// ---------------------------------------------------------------------------
// No-LDS fp16 hi/lo MFMA GEMM phase (R6-proven fragment path).
// task: x=n-tile(16), y=m-tile(2), z=k-slice. 8 waves, 64x32 per wave.
// ---------------------------------------------------------------------------
#define LOADSET(AH, AL, BH, BL, DISP)                                   \
    do {                                                                \
        _Pragma("unroll")                                               \
        for (int r = 0; r < 4; ++r) {                                   \
            AH[r] = *(const f16x8*)(pAh[r] + (DISP));                   \
            AL[r] = *(const f16x8*)(pAl[r] + (DISP));                   \
        }                                                               \
        _Pragma("unroll")                                               \
        for (int c = 0; c < 2; ++c) {                                   \
            BH[c] = *(const f16x8*)(pBh[c] + (DISP));                   \
            BL[c] = *(const f16x8*)(pBl[c] + (DISP));                   \
        }                                                               \
    } while (0)

#define MFMASET(AH, AL, BH, BL)                                                          \
    do {                                                                                 \
        _Pragma("unroll")                                                                \
        for (int r = 0; r < 4; ++r) {                                                    \
            _Pragma("unroll")                                                            \
            for (int c = 0; c < 2; ++c) {                                                \
                accH[r][c] = __builtin_amdgcn_mfma_f32_16x16x32_f16(AH[r], BH[c], accH[r][c], 0, 0, 0); \
                accC[r][c] = __builtin_amdgcn_mfma_f32_16x16x32_f16(AH[r], BL[c], accC[r][c], 0, 0, 0); \
                accC[r][c] = __builtin_amdgcn_mfma_f32_16x16x32_f16(AL[r], BH[c], accC[r][c], 0, 0, 0); \
            }                                                                            \
        }                                                                                \
    } while (0)

__device__ __forceinline__ void gemm_phase(
    const ushort_t* __restrict__ Ah, const ushort_t* __restrict__ Al,
    const ushort_t* __restrict__ Bth, const ushort_t* __restrict__ Btl,
    float* __restrict__ part, int K, int kchunk, int steps, int task, int tid)
{
    const int bn    = (task & 15) * 128;
    const int bm    = ((task >> 4) & 1) * 128;
    const int zz    = task >> 5;
    const int kbase = zz * kchunk;
    const int lane  = tid & 63;
    const int wv    = tid >> 6, wr = wv >> 2, wc = wv & 3;
    const int koff  = kbase + ((lane >> 4) << 3);

    const ushort_t* pAh[4]; const ushort_t* pAl[4];
    const ushort_t* pBh[2]; const ushort_t* pBl[2];
#pragma unroll
    for (int r = 0; r < 4; ++r) {
        const size_t o = (size_t)(bm + wr * 64 + r * 16 + (lane & 15)) * K + koff;
        pAh[r] = Ah + o; pAl[r] = Al + o;
    }
#pragma unroll
    for (int c = 0; c < 2; ++c) {
        const size_t o = (size_t)(bn + wc * 32 + c * 16 + (lane & 15)) * K + koff;
        pBh[c] = Bth + o; pBl[c] = Btl + o;
    }

    f32x4 accH[4][2], accC[4][2];
#pragma unroll
    for (int r = 0; r < 4; ++r)
#pragma unroll
        for (int c = 0; c < 2; ++c) {
            accH[r][c] = (f32x4){0.f, 0.f, 0.f, 0.f};
            accC[r][c] = (f32x4){0.f, 0.f, 0.f, 0.f};
        }

    f16x8 aH0[4], aL0[4], bH0[2], bL0[2];
    f16x8 aH1[4], aL1[4], bH1[2], bL1[2];

    int disp = 0;
    LOADSET(aH0, aL0, bH0, bL0, 0);
    for (int s = 0; s < steps; s += 2) {
        LOADSET(aH1, aL1, bH1, bL1, disp + 32);
        MFMASET(aH0, aL0, bH0, bL0);
        if (s + 2 < steps) LOADSET(aH0, aL0, bH0, bL0, disp + 64);
        MFMASET(aH1, aL1, bH1, bL1);
        disp += 64;
    }

    const float inv = 1.f / 4096.f;
    float* pout = part + (size_t)zz * 524288;
#pragma unroll
    for (int r = 0; r < 4; ++r)
#pragma unroll
        for (int c = 0; c < 2; ++c) {
            const int row = bm + wr * 64 + r * 16 + ((lane >> 4) << 2);
            const int col = bn + wc * 32 + c * 16 + (lane & 15);
#pragma unroll
            for (int e = 0; e < 4; ++e)
                pout[(size_t)(row + e) * 2048 + col] = accH[r][c][e] + accC[r][c][e] * inv;
        }
}

// ---------------------------------------------------------------------------
// Reduce KS partials + bias + relu; emit fp16 pairs (outH/outL) or fp32.
// 256 blocks x 512 threads: exactly one float4 per thread.
// ---------------------------------------------------------------------------
__device__ __forceinline__ void reduce_phase(
    const float* __restrict__ part, const float* __restrict__ bias, int KS,
    ushort_t* outH, ushort_t* outL, float* outF, int bid, int tid)
{
    const int lin = (bid * NT + tid) * 4;
    const int row = lin >> 11, col = lin & 2047;
    const size_t idx = (size_t)row * 2048 + col;
    float4 s = *(const float4*)&bias[col];
    for (int k = 0; k < KS; ++k) {
        const float4 p = *(const float4*)&part[(size_t)k * 524288 + idx];
        s.x += p.x; s.y += p.y; s.z += p.z; s.w += p.w;
    }
    s.x = fmaxf(s.x, 0.f); s.y = fmaxf(s.y, 0.f);
    s.z = fmaxf(s.z, 0.f); s.w = fmaxf(s.w, 0.f);
    if (outF) {
        *(float4*)&outF[idx] = s;
    } else {
        ushort_t h[4], l[4];
        split1(s.x, h[0], l[0]); split1(s.y, h[1], l[1]);
        split1(s.z, h[2], l[2]); split1(s.w, h[3], l[3]);
        ushort4 hv = {h[0], h[1], h[2], h[3]};
        ushort4 lv = {l[0], l[1], l[2], l[3]};
        *(ushort4*)&outH[idx] = hv;
        *(ushort4*)&outL[idx] = lv;
    }
}

// ---------------------------------------------------------------------------
// The fused persistent kernel: 256 blocks x 512 threads, 7 grid barriers.
// ---------------------------------------------------------------------------
__global__ __launch_bounds__(NT, 2) void fused_kernel(
    const float* __restrict__ z,
    const float* __restrict__ w0, const float* __restrict__ b0,
    const float* __restrict__ w1, const float* __restrict__ b1,
    const float* __restrict__ w2, const float* __restrict__ b2,
    const float* __restrict__ cvw, const float* __restrict__ cvb,
    const float* __restrict__ cw0, const float* __restrict__ cb0,
    const float* __restrict__ cw1, const float* __restrict__ cb1,
    const float* __restrict__ cw2, const float* __restrict__ cb2,
    const float* __restrict__ nw,  const float* __restrict__ nbv,
    const float* __restrict__ num_target, const int* __restrict__ cat_target,
    float* __restrict__ out, float* __restrict__ ws)
{
    __shared__ __align__(16) unsigned char smem[16640];
    const int bid = blockIdx.x;
    const int tid = threadIdx.x;

    // ---- workspace layout (bytes) ----
    char* base = (char*)ws;
    unsigned* bar  = (unsigned*)base;                          // 64 B
    float*    part = (float*)(base + 64);                      // 8 x 2 MB
    float*    rh2  = (float*)(base + 64 + 16777216);           // 2 MB
    float*    Mf   = (float*)(base + 64 + 18874368);           // 6 KB
    float*    beta = Mf + 1536;                                // 1 KB
    ushort_t* zh   = (ushort_t*)(base + 64 + 18874368 + 8192); // 128 KB
    ushort_t* zl   = zh + 65536;
    ushort_t* r0h  = zl + 65536;                               // 1 MB each
    ushort_t* r0l  = r0h + 524288;
    ushort_t* r1h  = r0l + 524288;
    ushort_t* r1l  = r1h + 524288;
    ushort_t* W0th = r1l + 524288;                             // 1 MB each
    ushort_t* W0tl = W0th + 524288;
    ushort_t* W1th = W0tl + 524288;                            // 8 MB each
    ushort_t* W1tl = W1th + 4194304;
    ushort_t* W2th = W1tl + 4194304;
    ushort_t* W2tl = W2th + 4194304;

    // ================= P0: W transpose+split | z split | head fusion =======
    for (int t = bid; t < 2342; t += NB) {
        __syncthreads();
        if (t < 2176) {
            ushort_t* lh = (ushort_t*)smem;       // [64][65]
            ushort_t* ll = lh + 4160;
            const float* src; ushort_t* dh; ushort_t* dl; int K, tt;
            if (t < 1024)      { src = w1; dh = W1th; dl = W1tl; K = 2048; tt = t; }
            else if (t < 2048) { src = w2; dh = W2th; dl = W2tl; K = 2048; tt = t - 1024; }
            else               { src = w0; dh = W0th; dl = W0tl; K = 256;  tt = t - 2048; }
            const int k0 = (tt >> 5) * 64;
            const int n0 = (tt & 31) * 64;
            {   // Phase A: read 64x64 fp32 tile, split, LDS [k][n]
                const int r = tid >> 3, cb = (tid & 7) * 8;
                const float* p = src + (size_t)(k0 + r) * 2048 + n0 + cb;
                float4 v0 = *(const float4*)p, v1 = *(const float4*)(p + 4);
                float fv[8] = {v0.x, v0.y, v0.z, v0.w, v1.x, v1.y, v1.z, v1.w};
#pragma unroll
                for (int j = 0; j < 8; ++j) {
                    ushort_t h, l;
                    split1(fv[j], h, l);
                    lh[r * 65 + cb + j] = h;
                    ll[r * 65 + cb + j] = l;
                }
            }
            __syncthreads();
            {   // Phase B: gather per-col, write Wt[col][k]
                const int c = tid >> 3, kb2 = (tid & 7) * 8;
                ushort_t hb[8], lb[8];
#pragma unroll
                for (int j = 0; j < 8; ++j) {
                    hb[j] = lh[(kb2 + j) * 65 + c];
                    lb[j] = ll[(kb2 + j) * 65 + c];
                }
                uint4 v;
                v.x = (unsigned)hb[0] | ((unsigned)hb[1] << 16);
                v.y = (unsigned)hb[2] | ((unsigned)hb[3] << 16);
                v.z = (unsigned)hb[4] | ((unsigned)hb[5] << 16);
                v.w = (unsigned)hb[6] | ((unsigned)hb[7] << 16);
                *(uint4*)(dh + (size_t)(n0 + c) * K + k0 + kb2) = v;
                v.x = (unsigned)lb[0] | ((unsigned)lb[1] << 16);
                v.y = (unsigned)lb[2] | ((unsigned)lb[3] << 16);
                v.z = (unsigned)lb[4] | ((unsigned)lb[5] << 16);
                v.w = (unsigned)lb[6] | ((unsigned)lb[7] << 16);
                *(uint4*)(dl + (size_t)(n0 + c) * K + k0 + kb2) = v;
            }
        } else if (t < 2192) {
            // z split: 16 tasks x 512 thr x 8 elems = 65536
            const int b2 = (t - 2176) * 4096 + tid * 8;
            float4 v0 = *(const float4*)&z[b2];
            float4 v1 = *(const float4*)&z[b2 + 4];
            float fv[8] = {v0.x, v0.y, v0.z, v0.w, v1.x, v1.y, v1.z, v1.w};
            uint4 hv, lv;
            pack8(fv, hv, lv);
            *(uint4*)&zh[b2] = hv;
            *(uint4*)&zl[b2] = lv;
        } else {
            // head fusion: one fused column per task
            const int k = t - 2192;
            const float* W; const float* B; int off, card;
            if (k < 4)        { W = cw0; B = cb0; off = 0;   card = 4;   }
            else if (k < 20)  { W = cw1; B = cb1; off = 4;   card = 16;  }
            else if (k < 148) { W = cw2; B = cb2; off = 20;  card = 128; }
            else              { W = nw;  B = nbv; off = 148; card = 2;   }
            const int kc = k - off;
            const int h = tid;                  // 512 threads = HH
            const float wv = W[h * card + kc];
            float pv[INCv + 1];
#pragma unroll
            for (int c = 0; c < INCv; ++c) pv[c] = cvw[h * INCv + c] * wv;
            pv[INCv] = cvb[h] * wv;
            float* redf = (float*)smem;         // [9][8]
            const int lane = tid & 63, wave = tid >> 6;
#pragma unroll
            for (int c = 0; c <= INCv; ++c) {
                float v = pv[c];
#pragma unroll
                for (int o = 32; o >= 1; o >>= 1) v += __shfl_down(v, o, 64);
                if (lane == 0) redf[c * 8 + wave] = v;
            }
            __syncthreads();
            if (tid <= INCv) {
                float s = 0.f;
#pragma unroll
                for (int wqq = 0; wqq < 8; ++wqq) s += redf[tid * 8 + wqq];
                if (tid < INCv) Mf[tid * NCOLS + k] = s;
                else            beta[k] = s + B[kc];
            }
        }
    }
    gsync(bar, bid);

    // ================= P1: layer0 GEMM (K=256, 4 k-slices, 128 tasks) ======
    if (bid < 128) gemm_phase(zh, zl, W0th, W0tl, part, 256, 64, 2, bid, tid);
    gsync(bar, bid);

    // ================= P2: reduce0 -> r0 fp16 pairs ========================
    reduce_phase(part, b0, 4, r0h, r0l, nullptr, bid, tid);
    gsync(bar, bid);

    // ================= P3: layer1 GEMM (K=2048, 8 slices) ==================
    gemm_phase(r0h, r0l, W1th, W1tl, part, 2048, 256, 8, bid, tid);
    gsync(bar, bid);

    // ================= P4: reduce1 -> r1 fp16 pairs ========================
    reduce_phase(part, b1, 8, r1h, r1l, nullptr, bid, tid);
    gsync(bar, bid);

    // ================= P5: layer2 GEMM =====================================
    gemm_phase(r1h, r1l, W2th, W2tl, part, 2048, 256, 8, bid, tid);
    gsync(bar, bid);

    // ================= P6: reduce2 -> rh2 fp32 =============================
    reduce_phase(part, b2, 8, nullptr, nullptr, rh2, bid, tid);
    gsync(bar, bid);

    // ================= P7: heads ===========================================
    if (bid < 48) {
        const int g = bid >> 4;
        const int card = (g == 0) ? 4 : (g == 1) ? 16 : 128;
        const int off  = (g == 0) ? 0 : (g == 1) ? 4  : 20;
        float* Msf  = (float*)smem;         // [8][128]
        float* Bshf = Msf + 1024;           // [128]
        for (int i = tid; i < card * INCv; i += NT)
            Msf[(i / card) * 128 + (i % card)] = Mf[(i / card) * NCOLS + off + (i % card)];
        for (int i = tid; i < card; i += NT) Bshf[i] = beta[off + i];
        __syncthreads();

        const int lin = bid * NT + tid;     // 0..24575
        const int r = lin & 8191;
        const int n = r >> 5, j = r & 31;
        const int ci = g * 32 + j;
        const int l  = ci * 2;
        float rv[INCv];
#pragma unroll
        for (int c = 0; c < INCv; ++c) rv[c] = rh2[n * MLPHv + c * LL + l];

        float mx = -1e30f; int arg = 0;
        for (int k = 0; k < card; ++k) {
            float s = Bshf[k];
#pragma unroll
            for (int c = 0; c < INCv; ++c) s += rv[c] * Msf[c * 128 + k];
            if (s > mx) { mx = s; arg = k; }
        }
        const int tg = cat_target[n * 96 + ci];
        float sum = 0.f, stg = 0.f;
        for (int k = 0; k < card; ++k) {
            float s = Bshf[k];
#pragma unroll
            for (int c = 0; c < INCv; ++c) s += rv[c] * Msf[c * 128 + k];
            sum += expf(s - mx);
            if (k == tg) stg = s;
        }
        const float lse = mx + logf(sum);
        out[NN * LL * 3 + n * 96 + ci] = lse - stg;
        float* u = out + (size_t)(n * LL + l) * 3;
        u[0] = (float)arg; u[1] = 0.f; u[2] = 0.f;
    } else if (bid < 128) {
        const int idx = (bid - 48) * NT + tid;   // 0..40959
        const int n = idx / 160, ni = idx % 160;
        const int l = (ni < 96) ? (2 * ni + 1) : (96 + ni);
        float rv[INCv];
#pragma unroll
        for (int c = 0; c < INCv; ++c) rv[c] = rh2[n * MLPHv + c * LL + l];
        float p0 = beta[148], p1 = beta[149];
#pragma unroll
        for (int c = 0; c < INCv; ++c) {
            p0 += rv[c] * Mf[c * NCOLS + 148];
            p1 += rv[c] * Mf[c * NCOLS + 149];
        }
        const float mu = 1.f / (1.f + expf(-p0));
        const float sp = (p1 > 20.f) ? p1 : log1pf(expf(p1));
        const float s  = sp + 1e-4f;
        const float hb = 1.f / 198.f;
        const float t  = num_target[n * 160 + ni];
        const float cp = 1.f / (1.f + expf(-((t + hb - mu) / s)));
        const float cm = 1.f / (1.f + expf(-((t - hb - mu) / s)));
        const float prob = (t < hb) ? cp : ((t > 1.f - hb) ? (1.f - cm) : (cp - cm));
        out[NN * LL * 3 + NN * 96 + n * 160 + ni] = -logf(fmaxf(prob, 1e-7f));
        float* u = out + (size_t)(n * LL + l) * 3;
        u[0] = 0.f; u[1] = rintf(mu * 99.f) / 99.f; u[2] = 0.f;
    }
}

// ---------------------------------------------------------------------------
extern "C" void kernel_launch(void* const* d_in, const int* in_sizes, int n_in,
                              void* d_out, int out_size, void* d_ws, size_t ws_size,
                              hipStream_t stream)
{
    const float* z   = (const float*)d_in[0];
    const float* w0  = (const float*)d_in[1];
    const float* b0  = (const float*)d_in[2];
    const float* w1  = (const float*)d_in[3];
    const float* b1  = (const float*)d_in[4];
    const float* w2  = (const float*)d_in[5];
    const float* b2  = (const float*)d_in[6];
    const float* cvw = (const float*)d_in[7];
    const float* cvb = (const float*)d_in[8];
    const float* cw0 = (const float*)d_in[9];
    const float* cb0 = (const float*)d_in[10];
    const float* cw1 = (const float*)d_in[11];
    const float* cb1 = (const float*)d_in[12];
    const float* cw2 = (const float*)d_in[13];
    const float* cb2 = (const float*)d_in[14];
    const float* nw  = (const float*)d_in[15];
    const float* nb  = (const float*)d_in[16];
    const float* num_target = (const float*)d_in[17];
    const int*   cat_target = (const int*)d_in[18];

    // reset grid-barrier state (deterministic per replay)
    hipMemsetAsync(d_ws, 0, 64, stream);

    fused_kernel<<<dim3(NB), dim3(NT), 0, stream>>>(
        z, w0, b0, w1, b1, w2, b2, cvw, cvb,
        cw0, cb0, cw1, cb1, cw2, cb2, nw, nb,
        num_target, cat_target, (float*)d_out, (float*)d_ws);
}

// Round 8
// 346.092 us; speedup vs baseline: 2.7911x; 2.7911x over previous
//
#include <hip/hip_runtime.h>
#include <hip/hip_fp16.h>
#include <math.h>

#define NN   256
#define LL   256
#define HH   512
#define MLPHv 2048
#define INCv 8
#define NCOLS 150

typedef _Float16 f16x8 __attribute__((ext_vector_type(8)));
typedef float    f32x4 __attribute__((ext_vector_type(4)));
typedef unsigned short ushort_t;

// ---------------------------------------------------------------------------
// fp32 -> fp16 hi/lo split:  a ≈ hi + lo/4096, |residual| <= 2^-22 |a|.
// ---------------------------------------------------------------------------
__device__ __forceinline__ void split1(float f, ushort_t& h, ushort_t& l)
{
    __half hh = __float2half_rn(f);
    h = __half_as_ushort(hh);
    l = __half_as_ushort(__float2half_rn((f - __half2float(hh)) * 4096.f));
}

__device__ __forceinline__ void pack8(const float* fv, uint4& hv, uint4& lv)
{
    ushort_t h[8], l[8];
#pragma unroll
    for (int j = 0; j < 8; ++j) split1(fv[j], h[j], l[j]);
    hv.x = (unsigned)h[0] | ((unsigned)h[1] << 16);
    hv.y = (unsigned)h[2] | ((unsigned)h[3] << 16);
    hv.z = (unsigned)h[4] | ((unsigned)h[5] << 16);
    hv.w = (unsigned)h[6] | ((unsigned)h[7] << 16);
    lv.x = (unsigned)l[0] | ((unsigned)l[1] << 16);
    lv.y = (unsigned)l[2] | ((unsigned)l[3] << 16);
    lv.z = (unsigned)l[4] | ((unsigned)l[5] << 16);
    lv.w = (unsigned)l[6] | ((unsigned)l[7] << 16);
}

// ---------------------------------------------------------------------------
// prep_all: bid<2176 -> W transpose+split 64x64 tiles (w1, w2, w0);
//           bid<2192 -> z split (16 blocks x 256 thr x 16 elems);
//           else     -> fused head weights (150 columns).
// ---------------------------------------------------------------------------
__global__ __launch_bounds__(256) void prep_all(
    const float* __restrict__ z,
    const float* __restrict__ w0, const float* __restrict__ w1,
    const float* __restrict__ w2,
    const float* __restrict__ cvw, const float* __restrict__ cvb,
    const float* __restrict__ cw0, const float* __restrict__ cb0,
    const float* __restrict__ cw1, const float* __restrict__ cb1,
    const float* __restrict__ cw2, const float* __restrict__ cb2,
    const float* __restrict__ nw,  const float* __restrict__ nbv,
    ushort_t* __restrict__ W0th, ushort_t* __restrict__ W0tl,
    ushort_t* __restrict__ W1th, ushort_t* __restrict__ W1tl,
    ushort_t* __restrict__ W2th, ushort_t* __restrict__ W2tl,
    ushort_t* __restrict__ zh, ushort_t* __restrict__ zl,
    float* __restrict__ Mf, float* __restrict__ beta)
{
    const int bid = blockIdx.x;
    const int tid = threadIdx.x;
    if (bid < 2176) {
        __shared__ ushort_t lh[64 * 65];
        __shared__ ushort_t ll[64 * 65];
        const float* src; ushort_t* dh; ushort_t* dl; int K, t;
        if (bid < 1024)      { src = w1; dh = W1th; dl = W1tl; K = 2048; t = bid; }
        else if (bid < 2048) { src = w2; dh = W2th; dl = W2tl; K = 2048; t = bid - 1024; }
        else                 { src = w0; dh = W0th; dl = W0tl; K = 256;  t = bid - 2048; }
        const int k0 = (t >> 5) * 64;
        const int n0 = (t & 31) * 64;
        {   // Phase A: read 64(k) x 64(n) fp32 tile, split, LDS [k][n]
            const int r  = tid >> 2;
            const int cb = (tid & 3) * 16;
            const float* p = src + (size_t)(k0 + r) * 2048 + n0 + cb;
            float fv[16];
#pragma unroll
            for (int q = 0; q < 4; ++q) {
                float4 v = *(const float4*)(p + q * 4);
                fv[q * 4 + 0] = v.x; fv[q * 4 + 1] = v.y;
                fv[q * 4 + 2] = v.z; fv[q * 4 + 3] = v.w;
            }
#pragma unroll
            for (int j = 0; j < 16; ++j) {
                ushort_t h, l;
                split1(fv[j], h, l);
                lh[r * 65 + cb + j] = h;
                ll[r * 65 + cb + j] = l;
            }
        }
        __syncthreads();
        {   // Phase B: per-col gather, write Wt[col][k]
            const int c   = tid >> 2;
            const int kb2 = (tid & 3) * 16;
            ushort_t hb[16], lb[16];
#pragma unroll
            for (int j = 0; j < 16; ++j) {
                hb[j] = lh[(kb2 + j) * 65 + c];
                lb[j] = ll[(kb2 + j) * 65 + c];
            }
            uint4 v0, v1;
            v0.x = (unsigned)hb[0]  | ((unsigned)hb[1]  << 16);
            v0.y = (unsigned)hb[2]  | ((unsigned)hb[3]  << 16);
            v0.z = (unsigned)hb[4]  | ((unsigned)hb[5]  << 16);
            v0.w = (unsigned)hb[6]  | ((unsigned)hb[7]  << 16);
            v1.x = (unsigned)hb[8]  | ((unsigned)hb[9]  << 16);
            v1.y = (unsigned)hb[10] | ((unsigned)hb[11] << 16);
            v1.z = (unsigned)hb[12] | ((unsigned)hb[13] << 16);
            v1.w = (unsigned)hb[14] | ((unsigned)hb[15] << 16);
            ushort_t* po = dh + (size_t)(n0 + c) * K + k0 + kb2;
            *(uint4*)po = v0;
            *(uint4*)(po + 8) = v1;
            v0.x = (unsigned)lb[0]  | ((unsigned)lb[1]  << 16);
            v0.y = (unsigned)lb[2]  | ((unsigned)lb[3]  << 16);
            v0.z = (unsigned)lb[4]  | ((unsigned)lb[5]  << 16);
            v0.w = (unsigned)lb[6]  | ((unsigned)lb[7]  << 16);
            v1.x = (unsigned)lb[8]  | ((unsigned)lb[9]  << 16);
            v1.y = (unsigned)lb[10] | ((unsigned)lb[11] << 16);
            v1.z = (unsigned)lb[12] | ((unsigned)lb[13] << 16);
            v1.w = (unsigned)lb[14] | ((unsigned)lb[15] << 16);
            po = dl + (size_t)(n0 + c) * K + k0 + kb2;
            *(uint4*)po = v0;
            *(uint4*)(po + 8) = v1;
        }
    } else if (bid < 2192) {
        // z split: 16 blocks x 256 thr x 16 elems = 65536
        const int base = (bid - 2176) * 4096 + tid * 16;
#pragma unroll
        for (int half = 0; half < 2; ++half) {
            const int b2 = base + half * 8;
            float4 v0 = *(const float4*)&z[b2];
            float4 v1 = *(const float4*)&z[b2 + 4];
            float fv[8] = {v0.x, v0.y, v0.z, v0.w, v1.x, v1.y, v1.z, v1.w};
            uint4 hv, lv;
            pack8(fv, hv, lv);
            *(uint4*)&zh[b2] = hv;
            *(uint4*)&zl[b2] = lv;
        }
    } else {
        // fused head weights: one column per block
        const int k = bid - 2192;
        const float* W; const float* B; int off, card;
        if (k < 4)        { W = cw0; B = cb0; off = 0;   card = 4;   }
        else if (k < 20)  { W = cw1; B = cb1; off = 4;   card = 16;  }
        else if (k < 148) { W = cw2; B = cb2; off = 20;  card = 128; }
        else              { W = nw;  B = nbv; off = 148; card = 2;   }
        const int kc = k - off;
        float part[INCv + 1];
#pragma unroll
        for (int c = 0; c <= INCv; ++c) part[c] = 0.f;
#pragma unroll
        for (int it = 0; it < 2; ++it) {
            const int h = tid + it * 256;
            const float wv = W[h * card + kc];
#pragma unroll
            for (int c = 0; c < INCv; ++c) part[c] += cvw[h * INCv + c] * wv;
            part[INCv] += cvb[h] * wv;
        }
        __shared__ float red[INCv + 1][4];
        const int lane = tid & 63, wave = tid >> 6;
#pragma unroll
        for (int c = 0; c <= INCv; ++c) {
            float v = part[c];
#pragma unroll
            for (int o = 32; o >= 1; o >>= 1) v += __shfl_down(v, o, 64);
            if (lane == 0) red[c][wave] = v;
        }
        __syncthreads();
        if (tid <= INCv) {
            const float s = red[tid][0] + red[tid][1] + red[tid][2] + red[tid][3];
            if (tid < INCv) Mf[tid * NCOLS + k] = s;
            else            beta[k] = s + B[kc];
        }
    }
}

// ---------------------------------------------------------------------------
// Single-pass no-LDS fp16 hi/lo MFMA GEMM, full K, fused epilogue.
// grid (32, 2): bn = bx*64, bm = by*128. 512 thr = 8 waves (2m x 4n),
// wave tile 64x16 (4 A-frags x 1 B-frag). Per K32: 10 loads, 12 MFMA.
// acc = ah*bh + (ah*bl + al*bh)/4096; epilogue bias+relu then
// OUT=0: fp16 hi/lo pairs; OUT=1: fp32.
// ---------------------------------------------------------------------------
#define LOADSET(AH, AL, BH, BL, DISP)                                   \
    do {                                                                \
        _Pragma("unroll")                                               \
        for (int r = 0; r < 4; ++r) {                                   \
            AH[r] = *(const f16x8*)(pAh[r] + (DISP));                   \
            AL[r] = *(const f16x8*)(pAl[r] + (DISP));                   \
        }                                                               \
        BH = *(const f16x8*)(pBh + (DISP));                             \
        BL = *(const f16x8*)(pBl + (DISP));                             \
    } while (0)

#define MFMASET(AH, AL, BH, BL)                                                          \
    do {                                                                                 \
        _Pragma("unroll")                                                                \
        for (int r = 0; r < 4; ++r) {                                                    \
            accH[r] = __builtin_amdgcn_mfma_f32_16x16x32_f16(AH[r], BH, accH[r], 0, 0, 0); \
            accC[r] = __builtin_amdgcn_mfma_f32_16x16x32_f16(AH[r], BL, accC[r], 0, 0, 0); \
            accC[r] = __builtin_amdgcn_mfma_f32_16x16x32_f16(AL[r], BH, accC[r], 0, 0, 0); \
        }                                                                                \
    } while (0)

template <int OUT>
__global__ __launch_bounds__(512) void gemm_ns(
    const ushort_t* __restrict__ Ah, const ushort_t* __restrict__ Al,
    const ushort_t* __restrict__ Bth, const ushort_t* __restrict__ Btl,
    const float* __restrict__ bias,
    ushort_t* __restrict__ outH, ushort_t* __restrict__ outL,
    float* __restrict__ outF, int K)
{
    const int tid  = threadIdx.x;
    const int bn   = blockIdx.x * 64;
    const int bm   = blockIdx.y * 128;
    const int lane = tid & 63;
    const int wv   = tid >> 6, wr = wv >> 2, wc = wv & 3;
    const int koff = (lane >> 4) << 3;
    const int steps = K >> 5;

    const ushort_t* pAh[4]; const ushort_t* pAl[4];
#pragma unroll
    for (int r = 0; r < 4; ++r) {
        const size_t o = (size_t)(bm + wr * 64 + r * 16 + (lane & 15)) * K + koff;
        pAh[r] = Ah + o; pAl[r] = Al + o;
    }
    const size_t ob = (size_t)(bn + wc * 16 + (lane & 15)) * K + koff;
    const ushort_t* pBh = Bth + ob;
    const ushort_t* pBl = Btl + ob;

    f32x4 accH[4], accC[4];
#pragma unroll
    for (int r = 0; r < 4; ++r) {
        accH[r] = (f32x4){0.f, 0.f, 0.f, 0.f};
        accC[r] = (f32x4){0.f, 0.f, 0.f, 0.f};
    }

    f16x8 aH0[4], aL0[4], aH1[4], aL1[4];
    f16x8 bH0, bL0, bH1, bL1;

    int disp = 0;
    LOADSET(aH0, aL0, bH0, bL0, 0);
    for (int s = 0; s < steps; s += 2) {
        LOADSET(aH1, aL1, bH1, bL1, disp + 32);
        MFMASET(aH0, aL0, bH0, bL0);
        if (s + 2 < steps) LOADSET(aH0, aL0, bH0, bL0, disp + 64);
        MFMASET(aH1, aL1, bH1, bL1);
        disp += 64;
    }

    const float inv = 1.f / 4096.f;
    const int col = bn + wc * 16 + (lane & 15);
    const float vb = bias[col];
#pragma unroll
    for (int r = 0; r < 4; ++r) {
        const int row = bm + wr * 64 + r * 16 + ((lane >> 4) << 2);
#pragma unroll
        for (int e = 0; e < 4; ++e) {
            float v = fmaxf(accH[r][e] + accC[r][e] * inv + vb, 0.f);
            if (OUT == 0) {
                ushort_t h, l;
                split1(v, h, l);
                outH[(size_t)(row + e) * 2048 + col] = h;
                outL[(size_t)(row + e) * 2048 + col] = l;
            } else {
                outF[(size_t)(row + e) * 2048 + col] = v;
            }
        }
    }
}

// ---------------------------------------------------------------------------
// Heads: bx<96 -> cat (g = bx>>5), bx>=96 -> num.
// ---------------------------------------------------------------------------
__global__ __launch_bounds__(256) void heads_kernel(
    const float* __restrict__ rh, const float* __restrict__ Mf,
    const float* __restrict__ beta, const int* __restrict__ cat_target,
    const float* __restrict__ num_target, float* __restrict__ out)
{
    const int bx  = blockIdx.x;
    const int tid = threadIdx.x;
    __shared__ float Ms[INCv][128];
    __shared__ float Bsh[128];
    if (bx < 96) {
        const int g = bx >> 5;
        const int card = (g == 0) ? 4 : (g == 1) ? 16 : 128;
        const int off  = (g == 0) ? 0 : (g == 1) ? 4  : 20;
        for (int i = tid; i < card * INCv; i += 256) {
            int c = i / card, k = i % card;
            Ms[c][k] = Mf[c * NCOLS + off + k];
        }
        for (int i = tid; i < card; i += 256) Bsh[i] = beta[off + i];
        __syncthreads();

        const int idx = (bx & 31) * 256 + tid;
        const int n = idx >> 5, j = idx & 31;
        const int ci = g * 32 + j;
        const int l  = ci * 2;
        float rv[INCv];
#pragma unroll
        for (int c = 0; c < INCv; ++c) rv[c] = rh[n * MLPHv + c * LL + l];

        float mx = -1e30f; int arg = 0;
        for (int k = 0; k < card; ++k) {
            float s = Bsh[k];
#pragma unroll
            for (int c = 0; c < INCv; ++c) s += rv[c] * Ms[c][k];
            if (s > mx) { mx = s; arg = k; }
        }
        const int tg = cat_target[n * 96 + ci];
        float sum = 0.f, stg = 0.f;
        for (int k = 0; k < card; ++k) {
            float s = Bsh[k];
#pragma unroll
            for (int c = 0; c < INCv; ++c) s += rv[c] * Ms[c][k];
            sum += expf(s - mx);
            if (k == tg) stg = s;
        }
        const float lse = mx + logf(sum);
        out[NN * LL * 3 + n * 96 + ci] = lse - stg;
        float* u = out + (size_t)(n * LL + l) * 3;
        u[0] = (float)arg; u[1] = 0.f; u[2] = 0.f;
    } else {
        const int idx = (bx - 96) * 256 + tid;  // 0..40959
        const int n = idx / 160, ni = idx % 160;
        const int l = (ni < 96) ? (2 * ni + 1) : (96 + ni);
        float rv[INCv];
#pragma unroll
        for (int c = 0; c < INCv; ++c) rv[c] = rh[n * MLPHv + c * LL + l];
        float p0 = beta[148], p1 = beta[149];
#pragma unroll
        for (int c = 0; c < INCv; ++c) {
            p0 += rv[c] * Mf[c * NCOLS + 148];
            p1 += rv[c] * Mf[c * NCOLS + 149];
        }
        const float mu = 1.f / (1.f + expf(-p0));
        const float sp = (p1 > 20.f) ? p1 : log1pf(expf(p1));
        const float s  = sp + 1e-4f;
        const float hb = 1.f / 198.f;
        const float t  = num_target[n * 160 + ni];
        const float cp = 1.f / (1.f + expf(-((t + hb - mu) / s)));
        const float cm = 1.f / (1.f + expf(-((t - hb - mu) / s)));
        const float prob = (t < hb) ? cp : ((t > 1.f - hb) ? (1.f - cm) : (cp - cm));
        out[NN * LL * 3 + NN * 96 + n * 160 + ni] = -logf(fmaxf(prob, 1e-7f));
        float* u = out + (size_t)(n * LL + l) * 3;
        u[0] = 0.f; u[1] = rintf(mu * 99.f) / 99.f; u[2] = 0.f;
    }
}

// ---------------------------------------------------------------------------
extern "C" void kernel_launch(void* const* d_in, const int* in_sizes, int n_in,
                              void* d_out, int out_size, void* d_ws, size_t ws_size,
                              hipStream_t stream)
{
    const float* z   = (const float*)d_in[0];
    const float* w0  = (const float*)d_in[1];
    const float* b0  = (const float*)d_in[2];
    const float* w1  = (const float*)d_in[3];
    const float* b1  = (const float*)d_in[4];
    const float* w2  = (const float*)d_in[5];
    const float* b2  = (const float*)d_in[6];
    const float* cvw = (const float*)d_in[7];
    const float* cvb = (const float*)d_in[8];
    const float* cw0 = (const float*)d_in[9];
    const float* cb0 = (const float*)d_in[10];
    const float* cw1 = (const float*)d_in[11];
    const float* cb1 = (const float*)d_in[12];
    const float* cw2 = (const float*)d_in[13];
    const float* cb2 = (const float*)d_in[14];
    const float* nw  = (const float*)d_in[15];
    const float* nb  = (const float*)d_in[16];
    const float* num_target = (const float*)d_in[17];
    const int*   cat_target = (const int*)d_in[18];
    float* out = (float*)d_out;
    float* ws  = (float*)d_ws;

    size_t o = 0;
    float*    rh2  = ws + o;                o += 524288;
    float*    Mf   = ws + o;                o += 1536;
    float*    beta = ws + o;                o += 256;
    ushort_t* zh   = (ushort_t*)(ws + o);   o += 32768;
    ushort_t* zl   = (ushort_t*)(ws + o);   o += 32768;
    ushort_t* r0h  = (ushort_t*)(ws + o);   o += 262144;
    ushort_t* r0l  = (ushort_t*)(ws + o);   o += 262144;
    ushort_t* r1h  = (ushort_t*)(ws + o);   o += 262144;
    ushort_t* r1l  = (ushort_t*)(ws + o);   o += 262144;
    ushort_t* W0th = (ushort_t*)(ws + o);   o += 262144;
    ushort_t* W0tl = (ushort_t*)(ws + o);   o += 262144;
    ushort_t* W1th = (ushort_t*)(ws + o);   o += 2097152;
    ushort_t* W1tl = (ushort_t*)(ws + o);   o += 2097152;
    ushort_t* W2th = (ushort_t*)(ws + o);   o += 2097152;
    ushort_t* W2tl = (ushort_t*)(ws + o);   o += 2097152;

    // 1. prep: W transpose+split | z split | head fusion
    prep_all<<<dim3(2342), 256, 0, stream>>>(
        z, w0, w1, w2, cvw, cvb, cw0, cb0, cw1, cb1, cw2, cb2, nw, nb,
        W0th, W0tl, W1th, W1tl, W2th, W2tl, zh, zl, Mf, beta);

    // 2. layer 0: r0 = relu(z@w0+b0) -> fp16 pairs  (K=256)
    gemm_ns<0><<<dim3(32, 2), 512, 0, stream>>>(
        zh, zl, W0th, W0tl, b0, r0h, r0l, nullptr, 256);

    // 3. layer 1: r1 = relu(r0@w1+b1) -> fp16 pairs (K=2048)
    gemm_ns<0><<<dim3(32, 2), 512, 0, stream>>>(
        r0h, r0l, W1th, W1tl, b1, r1h, r1l, nullptr, 2048);

    // 4. layer 2: rh2 = relu(r1@w2+b2) -> fp32      (K=2048)
    gemm_ns<1><<<dim3(32, 2), 512, 0, stream>>>(
        r1h, r1l, W2th, W2tl, b2, nullptr, nullptr, rh2, 2048);

    // 5. heads
    heads_kernel<<<dim3(256), 256, 0, stream>>>(
        rh2, Mf, beta, cat_target, num_target, out);
}

// Round 9
// 228.103 us; speedup vs baseline: 4.2349x; 1.5173x over previous
//
#include <hip/hip_runtime.h>
#include <hip/hip_fp16.h>
#include <math.h>

#define NN   256
#define LL   256
#define HH   512
#define MLPHv 2048
#define INCv 8
#define NCOLS 150

typedef _Float16 f16x8 __attribute__((ext_vector_type(8)));
typedef float    f32x4 __attribute__((ext_vector_type(4)));
typedef unsigned short ushort_t;

// ---------------------------------------------------------------------------
// fp32 -> fp16 hi/lo split:  a ≈ hi + lo/4096, |residual| <= 2^-22 |a|.
// ---------------------------------------------------------------------------
__device__ __forceinline__ void split1(float f, ushort_t& h, ushort_t& l)
{
    __half hh = __float2half_rn(f);
    h = __half_as_ushort(hh);
    l = __half_as_ushort(__float2half_rn((f - __half2float(hh)) * 4096.f));
}

__device__ __forceinline__ void pack8(const float* fv, uint4& hv, uint4& lv)
{
    ushort_t h[8], l[8];
#pragma unroll
    for (int j = 0; j < 8; ++j) split1(fv[j], h[j], l[j]);
    hv.x = (unsigned)h[0] | ((unsigned)h[1] << 16);
    hv.y = (unsigned)h[2] | ((unsigned)h[3] << 16);
    hv.z = (unsigned)h[4] | ((unsigned)h[5] << 16);
    hv.w = (unsigned)h[6] | ((unsigned)h[7] << 16);
    lv.x = (unsigned)l[0] | ((unsigned)l[1] << 16);
    lv.y = (unsigned)l[2] | ((unsigned)l[3] << 16);
    lv.z = (unsigned)l[4] | ((unsigned)l[5] << 16);
    lv.w = (unsigned)l[6] | ((unsigned)l[7] << 16);
}

// ---------------------------------------------------------------------------
// prep_all: bid<2176 -> W transpose+split 64x64 tiles (w1, w2, w0);
//           bid<2192 -> z split; else -> fused head weights (150 columns).
// ---------------------------------------------------------------------------
__global__ __launch_bounds__(256) void prep_all(
    const float* __restrict__ z,
    const float* __restrict__ w0, const float* __restrict__ w1,
    const float* __restrict__ w2,
    const float* __restrict__ cvw, const float* __restrict__ cvb,
    const float* __restrict__ cw0, const float* __restrict__ cb0,
    const float* __restrict__ cw1, const float* __restrict__ cb1,
    const float* __restrict__ cw2, const float* __restrict__ cb2,
    const float* __restrict__ nw,  const float* __restrict__ nbv,
    ushort_t* __restrict__ W0th, ushort_t* __restrict__ W0tl,
    ushort_t* __restrict__ W1th, ushort_t* __restrict__ W1tl,
    ushort_t* __restrict__ W2th, ushort_t* __restrict__ W2tl,
    ushort_t* __restrict__ zh, ushort_t* __restrict__ zl,
    float* __restrict__ Mf, float* __restrict__ beta)
{
    const int bid = blockIdx.x;
    const int tid = threadIdx.x;
    if (bid < 2176) {
        __shared__ ushort_t lh[64 * 65];
        __shared__ ushort_t ll[64 * 65];
        const float* src; ushort_t* dh; ushort_t* dl; int K, t;
        if (bid < 1024)      { src = w1; dh = W1th; dl = W1tl; K = 2048; t = bid; }
        else if (bid < 2048) { src = w2; dh = W2th; dl = W2tl; K = 2048; t = bid - 1024; }
        else                 { src = w0; dh = W0th; dl = W0tl; K = 256;  t = bid - 2048; }
        const int k0 = (t >> 5) * 64;
        const int n0 = (t & 31) * 64;
        {   // Phase A: read 64(k) x 64(n) fp32 tile, split, LDS [k][n]
            const int r  = tid >> 2;
            const int cb = (tid & 3) * 16;
            const float* p = src + (size_t)(k0 + r) * 2048 + n0 + cb;
            float fv[16];
#pragma unroll
            for (int q = 0; q < 4; ++q) {
                float4 v = *(const float4*)(p + q * 4);
                fv[q * 4 + 0] = v.x; fv[q * 4 + 1] = v.y;
                fv[q * 4 + 2] = v.z; fv[q * 4 + 3] = v.w;
            }
#pragma unroll
            for (int j = 0; j < 16; ++j) {
                ushort_t h, l;
                split1(fv[j], h, l);
                lh[r * 65 + cb + j] = h;
                ll[r * 65 + cb + j] = l;
            }
        }
        __syncthreads();
        {   // Phase B: per-col gather, write Wt[col][k]
            const int c   = tid >> 2;
            const int kb2 = (tid & 3) * 16;
            ushort_t hb[16], lb[16];
#pragma unroll
            for (int j = 0; j < 16; ++j) {
                hb[j] = lh[(kb2 + j) * 65 + c];
                lb[j] = ll[(kb2 + j) * 65 + c];
            }
            uint4 v0, v1;
            v0.x = (unsigned)hb[0]  | ((unsigned)hb[1]  << 16);
            v0.y = (unsigned)hb[2]  | ((unsigned)hb[3]  << 16);
            v0.z = (unsigned)hb[4]  | ((unsigned)hb[5]  << 16);
            v0.w = (unsigned)hb[6]  | ((unsigned)hb[7]  << 16);
            v1.x = (unsigned)hb[8]  | ((unsigned)hb[9]  << 16);
            v1.y = (unsigned)hb[10] | ((unsigned)hb[11] << 16);
            v1.z = (unsigned)hb[12] | ((unsigned)hb[13] << 16);
            v1.w = (unsigned)hb[14] | ((unsigned)hb[15] << 16);
            ushort_t* po = dh + (size_t)(n0 + c) * K + k0 + kb2;
            *(uint4*)po = v0;
            *(uint4*)(po + 8) = v1;
            v0.x = (unsigned)lb[0]  | ((unsigned)lb[1]  << 16);
            v0.y = (unsigned)lb[2]  | ((unsigned)lb[3]  << 16);
            v0.z = (unsigned)lb[4]  | ((unsigned)lb[5]  << 16);
            v0.w = (unsigned)lb[6]  | ((unsigned)lb[7]  << 16);
            v1.x = (unsigned)lb[8]  | ((unsigned)lb[9]  << 16);
            v1.y = (unsigned)lb[10] | ((unsigned)lb[11] << 16);
            v1.z = (unsigned)lb[12] | ((unsigned)lb[13] << 16);
            v1.w = (unsigned)lb[14] | ((unsigned)lb[15] << 16);
            po = dl + (size_t)(n0 + c) * K + k0 + kb2;
            *(uint4*)po = v0;
            *(uint4*)(po + 8) = v1;
        }
    } else if (bid < 2192) {
        // z split: 16 blocks x 256 thr x 16 elems = 65536
        const int base = (bid - 2176) * 4096 + tid * 16;
#pragma unroll
        for (int half = 0; half < 2; ++half) {
            const int b2 = base + half * 8;
            float4 v0 = *(const float4*)&z[b2];
            float4 v1 = *(const float4*)&z[b2 + 4];
            float fv[8] = {v0.x, v0.y, v0.z, v0.w, v1.x, v1.y, v1.z, v1.w};
            uint4 hv, lv;
            pack8(fv, hv, lv);
            *(uint4*)&zh[b2] = hv;
            *(uint4*)&zl[b2] = lv;
        }
    } else {
        // fused head weights: one column per block
        const int k = bid - 2192;
        const float* W; const float* B; int off, card;
        if (k < 4)        { W = cw0; B = cb0; off = 0;   card = 4;   }
        else if (k < 20)  { W = cw1; B = cb1; off = 4;   card = 16;  }
        else if (k < 148) { W = cw2; B = cb2; off = 20;  card = 128; }
        else              { W = nw;  B = nbv; off = 148; card = 2;   }
        const int kc = k - off;
        float part[INCv + 1];
#pragma unroll
        for (int c = 0; c <= INCv; ++c) part[c] = 0.f;
#pragma unroll
        for (int it = 0; it < 2; ++it) {
            const int h = tid + it * 256;
            const float wv = W[h * card + kc];
#pragma unroll
            for (int c = 0; c < INCv; ++c) part[c] += cvw[h * INCv + c] * wv;
            part[INCv] += cvb[h] * wv;
        }
        __shared__ float red[INCv + 1][4];
        const int lane = tid & 63, wave = tid >> 6;
#pragma unroll
        for (int c = 0; c <= INCv; ++c) {
            float v = part[c];
#pragma unroll
            for (int o = 32; o >= 1; o >>= 1) v += __shfl_down(v, o, 64);
            if (lane == 0) red[c][wave] = v;
        }
        __syncthreads();
        if (tid <= INCv) {
            const float s = red[tid][0] + red[tid][1] + red[tid][2] + red[tid][3];
            if (tid < INCv) Mf[tid * NCOLS + k] = s;
            else            beta[k] = s + B[kc];
        }
    }
}

// ---------------------------------------------------------------------------
// Single-pass no-LDS fp16 hi/lo MFMA GEMM, full K, fused epilogue.
// grid (32, 4): bn = bx*64, bm = by*64. 512 thr = 8 waves (2 wr x 4 wc),
// wave tile 32x16 (2 A-frags x 1 B-frag). Per K32: 6 loads, 6 MFMA.
// __launch_bounds__(512, 2): VGPR cap 256 so the ping-pong register
// pipeline survives (R8 failed: default bounds capped VGPR=64, compiler
// sank all loads -> serialized latency, 5400 cyc/step).
// acc = ah*bh + (ah*bl + al*bh)/4096; epilogue bias+relu then
// OUT=0: fp16 hi/lo pairs; OUT=1: fp32.
// ---------------------------------------------------------------------------
#define LOADSET(AH, AL, BH, BL, DISP)                                   \
    do {                                                                \
        _Pragma("unroll")                                               \
        for (int r = 0; r < 2; ++r) {                                   \
            AH[r] = *(const f16x8*)(pAh[r] + (DISP));                   \
            AL[r] = *(const f16x8*)(pAl[r] + (DISP));                   \
        }                                                               \
        BH = *(const f16x8*)(pBh + (DISP));                             \
        BL = *(const f16x8*)(pBl + (DISP));                             \
    } while (0)

#define MFMASET(AH, AL, BH, BL)                                                          \
    do {                                                                                 \
        _Pragma("unroll")                                                                \
        for (int r = 0; r < 2; ++r) {                                                    \
            accH[r] = __builtin_amdgcn_mfma_f32_16x16x32_f16(AH[r], BH, accH[r], 0, 0, 0); \
            accC[r] = __builtin_amdgcn_mfma_f32_16x16x32_f16(AH[r], BL, accC[r], 0, 0, 0); \
            accC[r] = __builtin_amdgcn_mfma_f32_16x16x32_f16(AL[r], BH, accC[r], 0, 0, 0); \
        }                                                                                \
    } while (0)

template <int OUT>
__global__ __launch_bounds__(512, 2) void gemm_ns(
    const ushort_t* __restrict__ Ah, const ushort_t* __restrict__ Al,
    const ushort_t* __restrict__ Bth, const ushort_t* __restrict__ Btl,
    const float* __restrict__ bias,
    ushort_t* __restrict__ outH, ushort_t* __restrict__ outL,
    float* __restrict__ outF, int K)
{
    const int tid  = threadIdx.x;
    const int bn   = blockIdx.x * 64;
    const int bm   = blockIdx.y * 64;
    const int lane = tid & 63;
    const int wv   = tid >> 6, wr = wv >> 2, wc = wv & 3;
    const int koff = (lane >> 4) << 3;
    const int steps = K >> 5;

    const ushort_t* pAh[2]; const ushort_t* pAl[2];
#pragma unroll
    for (int r = 0; r < 2; ++r) {
        const size_t o = (size_t)(bm + wr * 32 + r * 16 + (lane & 15)) * K + koff;
        pAh[r] = Ah + o; pAl[r] = Al + o;
    }
    const size_t ob = (size_t)(bn + wc * 16 + (lane & 15)) * K + koff;
    const ushort_t* pBh = Bth + ob;
    const ushort_t* pBl = Btl + ob;

    f32x4 accH[2], accC[2];
#pragma unroll
    for (int r = 0; r < 2; ++r) {
        accH[r] = (f32x4){0.f, 0.f, 0.f, 0.f};
        accC[r] = (f32x4){0.f, 0.f, 0.f, 0.f};
    }

    f16x8 aH0[2], aL0[2], aH1[2], aL1[2];
    f16x8 bH0, bL0, bH1, bL1;

    int disp = 0;
    LOADSET(aH0, aL0, bH0, bL0, 0);
    for (int s = 0; s < steps; s += 2) {
        LOADSET(aH1, aL1, bH1, bL1, disp + 32);
        MFMASET(aH0, aL0, bH0, bL0);
        if (s + 2 < steps) LOADSET(aH0, aL0, bH0, bL0, disp + 64);
        MFMASET(aH1, aL1, bH1, bL1);
        disp += 64;
    }

    const float inv = 1.f / 4096.f;
    const int col = bn + wc * 16 + (lane & 15);
    const float vb = bias[col];
#pragma unroll
    for (int r = 0; r < 2; ++r) {
        const int row = bm + wr * 32 + r * 16 + ((lane >> 4) << 2);
#pragma unroll
        for (int e = 0; e < 4; ++e) {
            float v = fmaxf(accH[r][e] + accC[r][e] * inv + vb, 0.f);
            if (OUT == 0) {
                ushort_t h, l;
                split1(v, h, l);
                outH[(size_t)(row + e) * 2048 + col] = h;
                outL[(size_t)(row + e) * 2048 + col] = l;
            } else {
                outF[(size_t)(row + e) * 2048 + col] = v;
            }
        }
    }
}

// ---------------------------------------------------------------------------
// Heads: bx<96 -> cat (g = bx>>5), bx>=96 -> num.
// ---------------------------------------------------------------------------
__global__ __launch_bounds__(256) void heads_kernel(
    const float* __restrict__ rh, const float* __restrict__ Mf,
    const float* __restrict__ beta, const int* __restrict__ cat_target,
    const float* __restrict__ num_target, float* __restrict__ out)
{
    const int bx  = blockIdx.x;
    const int tid = threadIdx.x;
    __shared__ float Ms[INCv][128];
    __shared__ float Bsh[128];
    if (bx < 96) {
        const int g = bx >> 5;
        const int card = (g == 0) ? 4 : (g == 1) ? 16 : 128;
        const int off  = (g == 0) ? 0 : (g == 1) ? 4  : 20;
        for (int i = tid; i < card * INCv; i += 256) {
            int c = i / card, k = i % card;
            Ms[c][k] = Mf[c * NCOLS + off + k];
        }
        for (int i = tid; i < card; i += 256) Bsh[i] = beta[off + i];
        __syncthreads();

        const int idx = (bx & 31) * 256 + tid;
        const int n = idx >> 5, j = idx & 31;
        const int ci = g * 32 + j;
        const int l  = ci * 2;
        float rv[INCv];
#pragma unroll
        for (int c = 0; c < INCv; ++c) rv[c] = rh[n * MLPHv + c * LL + l];

        float mx = -1e30f; int arg = 0;
        for (int k = 0; k < card; ++k) {
            float s = Bsh[k];
#pragma unroll
            for (int c = 0; c < INCv; ++c) s += rv[c] * Ms[c][k];
            if (s > mx) { mx = s; arg = k; }
        }
        const int tg = cat_target[n * 96 + ci];
        float sum = 0.f, stg = 0.f;
        for (int k = 0; k < card; ++k) {
            float s = Bsh[k];
#pragma unroll
            for (int c = 0; c < INCv; ++c) s += rv[c] * Ms[c][k];
            sum += expf(s - mx);
            if (k == tg) stg = s;
        }
        const float lse = mx + logf(sum);
        out[NN * LL * 3 + n * 96 + ci] = lse - stg;
        float* u = out + (size_t)(n * LL + l) * 3;
        u[0] = (float)arg; u[1] = 0.f; u[2] = 0.f;
    } else {
        const int idx = (bx - 96) * 256 + tid;  // 0..40959
        const int n = idx / 160, ni = idx % 160;
        const int l = (ni < 96) ? (2 * ni + 1) : (96 + ni);
        float rv[INCv];
#pragma unroll
        for (int c = 0; c < INCv; ++c) rv[c] = rh[n * MLPHv + c * LL + l];
        float p0 = beta[148], p1 = beta[149];
#pragma unroll
        for (int c = 0; c < INCv; ++c) {
            p0 += rv[c] * Mf[c * NCOLS + 148];
            p1 += rv[c] * Mf[c * NCOLS + 149];
        }
        const float mu = 1.f / (1.f + expf(-p0));
        const float sp = (p1 > 20.f) ? p1 : log1pf(expf(p1));
        const float s  = sp + 1e-4f;
        const float hb = 1.f / 198.f;
        const float t  = num_target[n * 160 + ni];
        const float cp = 1.f / (1.f + expf(-((t + hb - mu) / s)));
        const float cm = 1.f / (1.f + expf(-((t - hb - mu) / s)));
        const float prob = (t < hb) ? cp : ((t > 1.f - hb) ? (1.f - cm) : (cp - cm));
        out[NN * LL * 3 + NN * 96 + n * 160 + ni] = -logf(fmaxf(prob, 1e-7f));
        float* u = out + (size_t)(n * LL + l) * 3;
        u[0] = 0.f; u[1] = rintf(mu * 99.f) / 99.f; u[2] = 0.f;
    }
}

// ---------------------------------------------------------------------------
extern "C" void kernel_launch(void* const* d_in, const int* in_sizes, int n_in,
                              void* d_out, int out_size, void* d_ws, size_t ws_size,
                              hipStream_t stream)
{
    const float* z   = (const float*)d_in[0];
    const float* w0  = (const float*)d_in[1];
    const float* b0  = (const float*)d_in[2];
    const float* w1  = (const float*)d_in[3];
    const float* b1  = (const float*)d_in[4];
    const float* w2  = (const float*)d_in[5];
    const float* b2  = (const float*)d_in[6];
    const float* cvw = (const float*)d_in[7];
    const float* cvb = (const float*)d_in[8];
    const float* cw0 = (const float*)d_in[9];
    const float* cb0 = (const float*)d_in[10];
    const float* cw1 = (const float*)d_in[11];
    const float* cb1 = (const float*)d_in[12];
    const float* cw2 = (const float*)d_in[13];
    const float* cb2 = (const float*)d_in[14];
    const float* nw  = (const float*)d_in[15];
    const float* nb  = (const float*)d_in[16];
    const float* num_target = (const float*)d_in[17];
    const int*   cat_target = (const int*)d_in[18];
    float* out = (float*)d_out;
    float* ws  = (float*)d_ws;

    size_t o = 0;
    float*    rh2  = ws + o;                o += 524288;
    float*    Mf   = ws + o;                o += 1536;
    float*    beta = ws + o;                o += 256;
    ushort_t* zh   = (ushort_t*)(ws + o);   o += 32768;
    ushort_t* zl   = (ushort_t*)(ws + o);   o += 32768;
    ushort_t* r0h  = (ushort_t*)(ws + o);   o += 262144;
    ushort_t* r0l  = (ushort_t*)(ws + o);   o += 262144;
    ushort_t* r1h  = (ushort_t*)(ws + o);   o += 262144;
    ushort_t* r1l  = (ushort_t*)(ws + o);   o += 262144;
    ushort_t* W0th = (ushort_t*)(ws + o);   o += 262144;
    ushort_t* W0tl = (ushort_t*)(ws + o);   o += 262144;
    ushort_t* W1th = (ushort_t*)(ws + o);   o += 2097152;
    ushort_t* W1tl = (ushort_t*)(ws + o);   o += 2097152;
    ushort_t* W2th = (ushort_t*)(ws + o);   o += 2097152;
    ushort_t* W2tl = (ushort_t*)(ws + o);   o += 2097152;

    // 1. prep: W transpose+split | z split | head fusion
    prep_all<<<dim3(2342), 256, 0, stream>>>(
        z, w0, w1, w2, cvw, cvb, cw0, cb0, cw1, cb1, cw2, cb2, nw, nb,
        W0th, W0tl, W1th, W1tl, W2th, W2tl, zh, zl, Mf, beta);

    // 2. layer 0: r0 = relu(z@w0+b0) -> fp16 pairs  (K=256)
    gemm_ns<0><<<dim3(32, 4), 512, 0, stream>>>(
        zh, zl, W0th, W0tl, b0, r0h, r0l, nullptr, 256);

    // 3. layer 1: r1 = relu(r0@w1+b1) -> fp16 pairs (K=2048)
    gemm_ns<0><<<dim3(32, 4), 512, 0, stream>>>(
        r0h, r0l, W1th, W1tl, b1, r1h, r1l, nullptr, 2048);

    // 4. layer 2: rh2 = relu(r1@w2+b2) -> fp32      (K=2048)
    gemm_ns<1><<<dim3(32, 4), 512, 0, stream>>>(
        r1h, r1l, W2th, W2tl, b2, nullptr, nullptr, rh2, 2048);

    // 5. heads
    heads_kernel<<<dim3(256), 256, 0, stream>>>(
        rh2, Mf, beta, cat_target, num_target, out);
}

// Round 10
// 81.346 us; speedup vs baseline: 11.8751x; 2.8041x over previous
//
#include <hip/hip_runtime.h>
#include <hip/hip_fp16.h>
#include <math.h>

#define NN   256
#define LL   256
#define HH   512
#define MLPHv 2048
#define INCv 8
#define NCOLS 150

typedef _Float16 f16x8 __attribute__((ext_vector_type(8)));
typedef float    f32x4 __attribute__((ext_vector_type(4)));
typedef unsigned short ushort_t;

// ---------------------------------------------------------------------------
// fp32 -> fp16 hi/lo split:  a ≈ hi + lo/4096, |residual| <= 2^-22 |a|.
// ---------------------------------------------------------------------------
__device__ __forceinline__ void split1(float f, ushort_t& h, ushort_t& l)
{
    __half hh = __float2half_rn(f);
    h = __half_as_ushort(hh);
    l = __half_as_ushort(__float2half_rn((f - __half2float(hh)) * 4096.f));
}

// async global->LDS 16B per lane: LDS dest = wave-uniform base + lane*16,
// global src per-lane. The compiler cannot sink/serialize this (no VGPR dst).
typedef __attribute__((address_space(3))) unsigned int lds_u32;
typedef __attribute__((address_space(1))) const unsigned int glb_u32;
__device__ __forceinline__ void gl_lds16(const ushort_t* g, ushort_t* l)
{
    __builtin_amdgcn_global_load_lds((glb_u32*)g, (lds_u32*)l, 16, 0, 0);
}

// Fragment-linear packing: element X[row][k] (X in {A[M][K], Wt[N][K]}) lives
// at ((g*KS32 + ks)*64 + lane)*8 + j   where g=row>>4, ks=k>>5,
// lane=(row&15)+16*((k>>3)&3), j=k&7.  One frag = 64 lanes x 16B = 1KB
// contiguous -> coalesced global_load_lds runs + conflict-free ds_read_b128.

// ---------------------------------------------------------------------------
// prep_all: bid<2176 -> W transpose+split+PACK (w1, w2, w0);
//           bid<2192 -> z split+PACK; else -> fused head weights.
// ---------------------------------------------------------------------------
__global__ __launch_bounds__(256) void prep_all(
    const float* __restrict__ z,
    const float* __restrict__ w0, const float* __restrict__ w1,
    const float* __restrict__ w2,
    const float* __restrict__ cvw, const float* __restrict__ cvb,
    const float* __restrict__ cw0, const float* __restrict__ cb0,
    const float* __restrict__ cw1, const float* __restrict__ cb1,
    const float* __restrict__ cw2, const float* __restrict__ cb2,
    const float* __restrict__ nw,  const float* __restrict__ nbv,
    ushort_t* __restrict__ W0th, ushort_t* __restrict__ W0tl,
    ushort_t* __restrict__ W1th, ushort_t* __restrict__ W1tl,
    ushort_t* __restrict__ W2th, ushort_t* __restrict__ W2tl,
    ushort_t* __restrict__ zh, ushort_t* __restrict__ zl,
    float* __restrict__ Mf, float* __restrict__ beta)
{
    const int bid = blockIdx.x;
    const int tid = threadIdx.x;
    if (bid < 2176) {
        __shared__ ushort_t lh[64 * 65];
        __shared__ ushort_t ll[64 * 65];
        const float* src; ushort_t* dh; ushort_t* dl; int KS32v, t;
        if (bid < 1024)      { src = w1; dh = W1th; dl = W1tl; KS32v = 64; t = bid; }
        else if (bid < 2048) { src = w2; dh = W2th; dl = W2tl; KS32v = 64; t = bid - 1024; }
        else                 { src = w0; dh = W0th; dl = W0tl; KS32v = 8;  t = bid - 2048; }
        const int k0 = (t >> 5) * 64;
        const int n0 = (t & 31) * 64;
        {   // Phase A: read 64(k) x 64(n) fp32 tile, split, LDS [k][n]
            const int r  = tid >> 2;
            const int cb = (tid & 3) * 16;
            const float* p = src + (size_t)(k0 + r) * 2048 + n0 + cb;
            float fv[16];
#pragma unroll
            for (int q = 0; q < 4; ++q) {
                float4 v = *(const float4*)(p + q * 4);
                fv[q * 4 + 0] = v.x; fv[q * 4 + 1] = v.y;
                fv[q * 4 + 2] = v.z; fv[q * 4 + 3] = v.w;
            }
#pragma unroll
            for (int j = 0; j < 16; ++j) {
                ushort_t h, l;
                split1(fv[j], h, l);
                lh[r * 65 + cb + j] = h;
                ll[r * 65 + cb + j] = l;
            }
        }
        __syncthreads();
        {   // Phase B: gather per-col 16 k's, write packed frags
            const int c  = tid >> 2;
            const int kq = tid & 3;
            ushort_t hb[16], lb[16];
#pragma unroll
            for (int j = 0; j < 16; ++j) {
                hb[j] = lh[(kq * 16 + j) * 65 + c];
                lb[j] = ll[(kq * 16 + j) * 65 + c];
            }
            const int gn  = (n0 + c) >> 4;
            const int l16 = c & 15;
#pragma unroll
            for (int o = 0; o < 2; ++o) {
                const int koct  = (k0 >> 3) + kq * 2 + o;
                const int ks    = koct >> 2, koct3 = koct & 3;
                const size_t off = ((size_t)(gn * KS32v + ks) * 64 + l16 + (koct3 << 4)) * 8;
                uint4 v;
                v.x = (unsigned)hb[o*8+0] | ((unsigned)hb[o*8+1] << 16);
                v.y = (unsigned)hb[o*8+2] | ((unsigned)hb[o*8+3] << 16);
                v.z = (unsigned)hb[o*8+4] | ((unsigned)hb[o*8+5] << 16);
                v.w = (unsigned)hb[o*8+6] | ((unsigned)hb[o*8+7] << 16);
                *(uint4*)&dh[off] = v;
                v.x = (unsigned)lb[o*8+0] | ((unsigned)lb[o*8+1] << 16);
                v.y = (unsigned)lb[o*8+2] | ((unsigned)lb[o*8+3] << 16);
                v.z = (unsigned)lb[o*8+4] | ((unsigned)lb[o*8+5] << 16);
                v.w = (unsigned)lb[o*8+6] | ((unsigned)lb[o*8+7] << 16);
                *(uint4*)&dl[off] = v;
            }
        }
    } else if (bid < 2192) {
        // z split+pack: idx -> row r, 16 k's. KS32=8.
        const int idx = (bid - 2176) * 256 + tid;   // 0..4095
        const int r = idx >> 4, kq = idx & 15;
        const float* p = z + (size_t)r * 256 + kq * 16;
        float fv[16];
#pragma unroll
        for (int q = 0; q < 4; ++q) {
            float4 v = *(const float4*)(p + q * 4);
            fv[q * 4 + 0] = v.x; fv[q * 4 + 1] = v.y;
            fv[q * 4 + 2] = v.z; fv[q * 4 + 3] = v.w;
        }
        ushort_t hb[16], lb[16];
#pragma unroll
        for (int j = 0; j < 16; ++j) split1(fv[j], hb[j], lb[j]);
        const int gm = r >> 4, l16 = r & 15;
#pragma unroll
        for (int o = 0; o < 2; ++o) {
            const int koct = kq * 2 + o;
            const int ks = koct >> 2, koct3 = koct & 3;
            const size_t off = ((size_t)(gm * 8 + ks) * 64 + l16 + (koct3 << 4)) * 8;
            uint4 v;
            v.x = (unsigned)hb[o*8+0] | ((unsigned)hb[o*8+1] << 16);
            v.y = (unsigned)hb[o*8+2] | ((unsigned)hb[o*8+3] << 16);
            v.z = (unsigned)hb[o*8+4] | ((unsigned)hb[o*8+5] << 16);
            v.w = (unsigned)hb[o*8+6] | ((unsigned)hb[o*8+7] << 16);
            *(uint4*)&zh[off] = v;
            v.x = (unsigned)lb[o*8+0] | ((unsigned)lb[o*8+1] << 16);
            v.y = (unsigned)lb[o*8+2] | ((unsigned)lb[o*8+3] << 16);
            v.z = (unsigned)lb[o*8+4] | ((unsigned)lb[o*8+5] << 16);
            v.w = (unsigned)lb[o*8+6] | ((unsigned)lb[o*8+7] << 16);
            *(uint4*)&zl[off] = v;
        }
    } else {
        // fused head weights: one column per block
        const int k = bid - 2192;
        const float* W; const float* B; int off, card;
        if (k < 4)        { W = cw0; B = cb0; off = 0;   card = 4;   }
        else if (k < 20)  { W = cw1; B = cb1; off = 4;   card = 16;  }
        else if (k < 148) { W = cw2; B = cb2; off = 20;  card = 128; }
        else              { W = nw;  B = nbv; off = 148; card = 2;   }
        const int kc = k - off;
        float part[INCv + 1];
#pragma unroll
        for (int c = 0; c <= INCv; ++c) part[c] = 0.f;
#pragma unroll
        for (int it = 0; it < 2; ++it) {
            const int h = tid + it * 256;
            const float wv = W[h * card + kc];
#pragma unroll
            for (int c = 0; c < INCv; ++c) part[c] += cvw[h * INCv + c] * wv;
            part[INCv] += cvb[h] * wv;
        }
        __shared__ float red[INCv + 1][4];
        const int lane = tid & 63, wave = tid >> 6;
#pragma unroll
        for (int c = 0; c <= INCv; ++c) {
            float v = part[c];
#pragma unroll
            for (int o = 32; o >= 1; o >>= 1) v += __shfl_down(v, o, 64);
            if (lane == 0) red[c][wave] = v;
        }
        __syncthreads();
        if (tid <= INCv) {
            const float s = red[tid][0] + red[tid][1] + red[tid][2] + red[tid][3];
            if (tid < INCv) Mf[tid * NCOLS + k] = s;
            else            beta[k] = s + B[kc];
        }
    }
}

// ---------------------------------------------------------------------------
// Packed-operand MFMA GEMM with async global_load_lds staging (m97 pattern).
// 512 thr = 8 waves (4 wr x 2 wc), BM=128, BN=64, BK=64, wave tile 32x32.
// LDS 48KB -> 3 blocks/CU (~20+ waves/CU latency hiding).
// Per step: 6 global_load_lds issues/thread, barrier, 16 ds_read_b128 +
// 24 MFMA per wave, barrier.  acc = ah*bh + (ah*bl + al*bh)/4096.
// OUT=0: fp32 partial at part + bz*524288.
// OUT=1: bias+relu then fp16 hi/lo split PACKED to oH/oL (KS32_next=64).
// ---------------------------------------------------------------------------
template <int OUT>
__global__ __launch_bounds__(512, 4) void gemm_pk(
    const ushort_t* __restrict__ Ah, const ushort_t* __restrict__ Al,
    const ushort_t* __restrict__ Bh, const ushort_t* __restrict__ Bl,
    const float* __restrict__ bias, float* __restrict__ part,
    ushort_t* __restrict__ oH, ushort_t* __restrict__ oL,
    int KS32, int kchunk32, int steps)
{
    __shared__ ushort_t sAh[8192];   // 8 gm x 2 ks x 64 x 8
    __shared__ ushort_t sAl[8192];
    __shared__ ushort_t sBh[4096];   // 4 gn x 2 ks x 64 x 8
    __shared__ ushort_t sBl[4096];

    const int tid  = threadIdx.x;
    const int lane = tid & 63, w = tid >> 6;
    const int wr   = w >> 1, wc = w & 1;
    const int bx   = blockIdx.x, by = blockIdx.y, bz = blockIdx.z;
    const int kb0  = bz * kchunk32;

    f32x4 accH[2][2], accC[2][2];
#pragma unroll
    for (int r = 0; r < 2; ++r)
#pragma unroll
        for (int c = 0; c < 2; ++c) {
            accH[r][c] = (f32x4){0.f, 0.f, 0.f, 0.f};
            accC[r][c] = (f32x4){0.f, 0.f, 0.f, 0.f};
        }

    for (int t = 0; t < steps; ++t) {
        const int kb = kb0 + t * 2;
        // ---- stage A: 2 runs per wave per plane (1KB each, coalesced) ----
#pragma unroll
        for (int i = 0; i < 2; ++i) {
            const int run = w + i * 8;           // 0..15 = gm_local*2 + ks
            const int g = run >> 1, ks = run & 1;
            const size_t f = ((size_t)(by * 8 + g) * KS32 + kb + ks) * 512 + lane * 8;
            gl_lds16(Ah + f, &sAh[run * 512]);
            gl_lds16(Al + f, &sAl[run * 512]);
        }
        // ---- stage B: 1 run per wave per plane ----
        {
            const int g = w >> 1, ks = w & 1;    // run = w
            const size_t f = ((size_t)(bx * 4 + g) * KS32 + kb + ks) * 512 + lane * 8;
            gl_lds16(Bh + f, &sBh[w * 512]);
            gl_lds16(Bl + f, &sBl[w * 512]);
        }
        __syncthreads();   // compiler drains vmcnt before barrier -> LDS valid

        // ---- MFMA over the two k32 slices ----
#pragma unroll
        for (int ks = 0; ks < 2; ++ks) {
            f16x8 aH[2], aL[2], bHf[2], bLf[2];
#pragma unroll
            for (int r = 0; r < 2; ++r) {
                const int off = (((wr * 2 + r) * 2 + ks) * 64 + lane) * 8;
                aH[r] = *(const f16x8*)&sAh[off];
                aL[r] = *(const f16x8*)&sAl[off];
            }
#pragma unroll
            for (int c = 0; c < 2; ++c) {
                const int off = (((wc * 2 + c) * 2 + ks) * 64 + lane) * 8;
                bHf[c] = *(const f16x8*)&sBh[off];
                bLf[c] = *(const f16x8*)&sBl[off];
            }
#pragma unroll
            for (int r = 0; r < 2; ++r)
#pragma unroll
                for (int c = 0; c < 2; ++c) {
                    accH[r][c] = __builtin_amdgcn_mfma_f32_16x16x32_f16(aH[r], bHf[c], accH[r][c], 0, 0, 0);
                    accC[r][c] = __builtin_amdgcn_mfma_f32_16x16x32_f16(aH[r], bLf[c], accC[r][c], 0, 0, 0);
                    accC[r][c] = __builtin_amdgcn_mfma_f32_16x16x32_f16(aL[r], bHf[c], accC[r][c], 0, 0, 0);
                }
        }
        __syncthreads();   // reads done before next stage overwrites
    }

    const float inv = 1.f / 4096.f;
#pragma unroll
    for (int r = 0; r < 2; ++r)
#pragma unroll
        for (int c = 0; c < 2; ++c) {
            const int row0 = by * 128 + (wr * 2 + r) * 16 + ((lane >> 4) << 2);
            const int col  = bx * 64  + (wc * 2 + c) * 16 + (lane & 15);
            if (OUT == 0) {
                float* po = part + (size_t)bz * 524288;
#pragma unroll
                for (int e = 0; e < 4; ++e)
                    po[(size_t)(row0 + e) * 2048 + col] = accH[r][c][e] + accC[r][c][e] * inv;
            } else {
                const float vb = bias[col];
                const int gm = (by * 8 + wr * 2 + r);
                const int ks = col >> 5, koct3 = (col >> 3) & 3, j = col & 7;
                const size_t fb = ((size_t)(gm * 64 + ks) * 64) * 8 + (koct3 << 4) * 8 + j;
#pragma unroll
                for (int e = 0; e < 4; ++e) {
                    const float v = fmaxf(accH[r][c][e] + accC[r][c][e] * inv + vb, 0.f);
                    ushort_t h, l;
                    split1(v, h, l);
                    const int l16 = ((lane >> 4) << 2) + e;
                    oH[fb + (size_t)l16 * 8] = h;
                    oL[fb + (size_t)l16 * 8] = l;
                }
            }
        }
}

// ---------------------------------------------------------------------------
// Reduce 4 partials + bias + relu. PACK: emit packed fp16 pairs (next
// layer's A, KS32=64); else fp32 (rh2 for heads).
// ---------------------------------------------------------------------------
template <bool PACK>
__global__ __launch_bounds__(256) void reduce_pk(
    const float* __restrict__ part, const float* __restrict__ bias,
    ushort_t* __restrict__ oH, ushort_t* __restrict__ oL, float* __restrict__ oF)
{
    const int b  = blockIdx.x;        // 512 blocks
    const int ct = b & 15, rg = b >> 4;
    const int e  = threadIdx.x * 4;
    const int row = rg * 8 + (e >> 7);
    const int col = ct * 128 + (e & 127);
    const size_t idx = (size_t)row * 2048 + col;
    float4 s = *(const float4*)&bias[col];
#pragma unroll
    for (int k = 0; k < 4; ++k) {
        const float4 p = *(const float4*)&part[(size_t)k * 524288 + idx];
        s.x += p.x; s.y += p.y; s.z += p.z; s.w += p.w;
    }
    s.x = fmaxf(s.x, 0.f); s.y = fmaxf(s.y, 0.f);
    s.z = fmaxf(s.z, 0.f); s.w = fmaxf(s.w, 0.f);
    if (PACK) {
        ushort_t h[4], l[4];
        split1(s.x, h[0], l[0]); split1(s.y, h[1], l[1]);
        split1(s.z, h[2], l[2]); split1(s.w, h[3], l[3]);
        const int gm = row >> 4, l16 = row & 15;
        const int ks = col >> 5, koct3 = (col >> 3) & 3, j = col & 7;
        const size_t off = ((size_t)(gm * 64 + ks) * 64 + l16 + (koct3 << 4)) * 8 + j;
        ushort4 hv = {h[0], h[1], h[2], h[3]};
        ushort4 lv = {l[0], l[1], l[2], l[3]};
        *(ushort4*)&oH[off] = hv;
        *(ushort4*)&oL[off] = lv;
    } else {
        *(float4*)&oF[idx] = s;
    }
}

// ---------------------------------------------------------------------------
// Heads: bx<96 -> cat (g = bx>>5), bx>=96 -> num.  (unchanged, proven)
// ---------------------------------------------------------------------------
__global__ __launch_bounds__(256) void heads_kernel(
    const float* __restrict__ rh, const float* __restrict__ Mf,
    const float* __restrict__ beta, const int* __restrict__ cat_target,
    const float* __restrict__ num_target, float* __restrict__ out)
{
    const int bx  = blockIdx.x;
    const int tid = threadIdx.x;
    __shared__ float Ms[INCv][128];
    __shared__ float Bsh[128];
    if (bx < 96) {
        const int g = bx >> 5;
        const int card = (g == 0) ? 4 : (g == 1) ? 16 : 128;
        const int off  = (g == 0) ? 0 : (g == 1) ? 4  : 20;
        for (int i = tid; i < card * INCv; i += 256) {
            int c = i / card, k = i % card;
            Ms[c][k] = Mf[c * NCOLS + off + k];
        }
        for (int i = tid; i < card; i += 256) Bsh[i] = beta[off + i];
        __syncthreads();

        const int idx = (bx & 31) * 256 + tid;
        const int n = idx >> 5, j = idx & 31;
        const int ci = g * 32 + j;
        const int l  = ci * 2;
        float rv[INCv];
#pragma unroll
        for (int c = 0; c < INCv; ++c) rv[c] = rh[n * MLPHv + c * LL + l];

        float mx = -1e30f; int arg = 0;
        for (int k = 0; k < card; ++k) {
            float s = Bsh[k];
#pragma unroll
            for (int c = 0; c < INCv; ++c) s += rv[c] * Ms[c][k];
            if (s > mx) { mx = s; arg = k; }
        }
        const int tg = cat_target[n * 96 + ci];
        float sum = 0.f, stg = 0.f;
        for (int k = 0; k < card; ++k) {
            float s = Bsh[k];
#pragma unroll
            for (int c = 0; c < INCv; ++c) s += rv[c] * Ms[c][k];
            sum += expf(s - mx);
            if (k == tg) stg = s;
        }
        const float lse = mx + logf(sum);
        out[NN * LL * 3 + n * 96 + ci] = lse - stg;
        float* u = out + (size_t)(n * LL + l) * 3;
        u[0] = (float)arg; u[1] = 0.f; u[2] = 0.f;
    } else {
        const int idx = (bx - 96) * 256 + tid;  // 0..40959
        const int n = idx / 160, ni = idx % 160;
        const int l = (ni < 96) ? (2 * ni + 1) : (96 + ni);
        float rv[INCv];
#pragma unroll
        for (int c = 0; c < INCv; ++c) rv[c] = rh[n * MLPHv + c * LL + l];
        float p0 = beta[148], p1 = beta[149];
#pragma unroll
        for (int c = 0; c < INCv; ++c) {
            p0 += rv[c] * Mf[c * NCOLS + 148];
            p1 += rv[c] * Mf[c * NCOLS + 149];
        }
        const float mu = 1.f / (1.f + expf(-p0));
        const float sp = (p1 > 20.f) ? p1 : log1pf(expf(p1));
        const float s  = sp + 1e-4f;
        const float hb = 1.f / 198.f;
        const float t  = num_target[n * 160 + ni];
        const float cp = 1.f / (1.f + expf(-((t + hb - mu) / s)));
        const float cm = 1.f / (1.f + expf(-((t - hb - mu) / s)));
        const float prob = (t < hb) ? cp : ((t > 1.f - hb) ? (1.f - cm) : (cp - cm));
        out[NN * LL * 3 + NN * 96 + n * 160 + ni] = -logf(fmaxf(prob, 1e-7f));
        float* u = out + (size_t)(n * LL + l) * 3;
        u[0] = 0.f; u[1] = rintf(mu * 99.f) / 99.f; u[2] = 0.f;
    }
}

// ---------------------------------------------------------------------------
extern "C" void kernel_launch(void* const* d_in, const int* in_sizes, int n_in,
                              void* d_out, int out_size, void* d_ws, size_t ws_size,
                              hipStream_t stream)
{
    const float* z   = (const float*)d_in[0];
    const float* w0  = (const float*)d_in[1];
    const float* b0  = (const float*)d_in[2];
    const float* w1  = (const float*)d_in[3];
    const float* b1  = (const float*)d_in[4];
    const float* w2  = (const float*)d_in[5];
    const float* b2  = (const float*)d_in[6];
    const float* cvw = (const float*)d_in[7];
    const float* cvb = (const float*)d_in[8];
    const float* cw0 = (const float*)d_in[9];
    const float* cb0 = (const float*)d_in[10];
    const float* cw1 = (const float*)d_in[11];
    const float* cb1 = (const float*)d_in[12];
    const float* cw2 = (const float*)d_in[13];
    const float* cb2 = (const float*)d_in[14];
    const float* nw  = (const float*)d_in[15];
    const float* nb  = (const float*)d_in[16];
    const float* num_target = (const float*)d_in[17];
    const int*   cat_target = (const int*)d_in[18];
    float* out = (float*)d_out;
    float* ws  = (float*)d_ws;

    size_t o = 0;
    float*    part = ws + o;                o += 4ull * 524288;   // 8 MB
    float*    rh2  = ws + o;                o += 524288;
    float*    Mf   = ws + o;                o += 1536;
    float*    beta = ws + o;                o += 256;
    ushort_t* zh   = (ushort_t*)(ws + o);   o += 32768;           // packed 256x256
    ushort_t* zl   = (ushort_t*)(ws + o);   o += 32768;
    ushort_t* r0h  = (ushort_t*)(ws + o);   o += 262144;          // packed 256x2048
    ushort_t* r0l  = (ushort_t*)(ws + o);   o += 262144;
    ushort_t* r1h  = (ushort_t*)(ws + o);   o += 262144;
    ushort_t* r1l  = (ushort_t*)(ws + o);   o += 262144;
    ushort_t* W0th = (ushort_t*)(ws + o);   o += 262144;          // packed 2048x256
    ushort_t* W0tl = (ushort_t*)(ws + o);   o += 262144;
    ushort_t* W1th = (ushort_t*)(ws + o);   o += 2097152;         // packed 2048x2048
    ushort_t* W1tl = (ushort_t*)(ws + o);   o += 2097152;
    ushort_t* W2th = (ushort_t*)(ws + o);   o += 2097152;
    ushort_t* W2tl = (ushort_t*)(ws + o);   o += 2097152;

    // 1. prep: W transpose+split+pack | z split+pack | head fusion
    prep_all<<<dim3(2342), 256, 0, stream>>>(
        z, w0, w1, w2, cvw, cvb, cw0, cb0, cw1, cb1, cw2, cb2, nw, nb,
        W0th, W0tl, W1th, W1tl, W2th, W2tl, zh, zl, Mf, beta);

    // 2. layer 0 (K=256, full-K, 64 blocks): r0 = pack(relu(z@w0+b0))
    gemm_pk<1><<<dim3(32, 2, 1), 512, 0, stream>>>(
        zh, zl, W0th, W0tl, b0, nullptr, r0h, r0l, 8, 8, 4);

    // 3-4. layer 1 (K=2048, splitK=4) + reduce -> r1 packed
    gemm_pk<0><<<dim3(32, 2, 4), 512, 0, stream>>>(
        r0h, r0l, W1th, W1tl, nullptr, part, nullptr, nullptr, 64, 16, 8);
    reduce_pk<true><<<dim3(512), 256, 0, stream>>>(part, b1, r1h, r1l, nullptr);

    // 5-6. layer 2 (K=2048, splitK=4) + reduce -> rh2 fp32
    gemm_pk<0><<<dim3(32, 2, 4), 512, 0, stream>>>(
        r1h, r1l, W2th, W2tl, nullptr, part, nullptr, nullptr, 64, 16, 8);
    reduce_pk<false><<<dim3(512), 256, 0, stream>>>(part, b2, nullptr, nullptr, rh2);

    // 7. heads
    heads_kernel<<<dim3(256), 256, 0, stream>>>(
        rh2, Mf, beta, cat_target, num_target, out);
}

// Round 11
// 77.808 us; speedup vs baseline: 12.4150x; 1.0455x over previous
//
#include <hip/hip_runtime.h>
#include <hip/hip_fp16.h>
#include <math.h>

#define NN   256
#define LL   256
#define HH   512
#define MLPHv 2048
#define INCv 8
#define NCOLS 150

typedef _Float16 f16x8 __attribute__((ext_vector_type(8)));
typedef float    f32x4 __attribute__((ext_vector_type(4)));
typedef unsigned short ushort_t;

// ---------------------------------------------------------------------------
// fp32 -> fp16 hi/lo split:  a ≈ hi + lo/4096, |residual| <= 2^-22 |a|.
// ---------------------------------------------------------------------------
__device__ __forceinline__ void split1(float f, ushort_t& h, ushort_t& l)
{
    __half hh = __float2half_rn(f);
    h = __half_as_ushort(hh);
    l = __half_as_ushort(__float2half_rn((f - __half2float(hh)) * 4096.f));
}

__device__ __forceinline__ void pack8(const float* fv, uint4& hv, uint4& lv)
{
    ushort_t h[8], l[8];
#pragma unroll
    for (int j = 0; j < 8; ++j) split1(fv[j], h[j], l[j]);
    hv.x = (unsigned)h[0] | ((unsigned)h[1] << 16);
    hv.y = (unsigned)h[2] | ((unsigned)h[3] << 16);
    hv.z = (unsigned)h[4] | ((unsigned)h[5] << 16);
    hv.w = (unsigned)h[6] | ((unsigned)h[7] << 16);
    lv.x = (unsigned)l[0] | ((unsigned)l[1] << 16);
    lv.y = (unsigned)l[2] | ((unsigned)l[3] << 16);
    lv.z = (unsigned)l[4] | ((unsigned)l[5] << 16);
    lv.w = (unsigned)l[6] | ((unsigned)l[7] << 16);
}

// async global->LDS 16B per lane (linear dest: base + lane*16).
typedef __attribute__((address_space(3))) unsigned int lds_u32;
typedef __attribute__((address_space(1))) const unsigned int glb_u32;
__device__ __forceinline__ void gl_lds16(const ushort_t* g, ushort_t* l)
{
    __builtin_amdgcn_global_load_lds((glb_u32*)g, (lds_u32*)l, 16, 0, 0);
}

// Fragment-linear packing (R10-proven): X[row][k] lives at
// ((g*KS32 + ks)*64 + lane)*8 + j,  g=row>>4, ks=k>>5,
// lane=(row&15)+16*((k>>3)&3), j=k&7.

// ---------------------------------------------------------------------------
// prep_all: bid<2176 -> W transpose+split+pack (fp32 LDS transpose);
//           bid<2192 -> z split+pack; else -> fused head weights.
// ---------------------------------------------------------------------------
__global__ __launch_bounds__(256) void prep_all(
    const float* __restrict__ z,
    const float* __restrict__ w0, const float* __restrict__ w1,
    const float* __restrict__ w2,
    const float* __restrict__ cvw, const float* __restrict__ cvb,
    const float* __restrict__ cw0, const float* __restrict__ cb0,
    const float* __restrict__ cw1, const float* __restrict__ cb1,
    const float* __restrict__ cw2, const float* __restrict__ cb2,
    const float* __restrict__ nw,  const float* __restrict__ nbv,
    ushort_t* __restrict__ W0th, ushort_t* __restrict__ W0tl,
    ushort_t* __restrict__ W1th, ushort_t* __restrict__ W1tl,
    ushort_t* __restrict__ W2th, ushort_t* __restrict__ W2tl,
    ushort_t* __restrict__ zh, ushort_t* __restrict__ zl,
    float* __restrict__ Mf, float* __restrict__ beta)
{
    const int bid = blockIdx.x;
    const int tid = threadIdx.x;
    if (bid < 2176) {
        __shared__ float lfs[64 * 68];   // [k][n] fp32, pad 68
        const float* src; ushort_t* dh; ushort_t* dl; int KS32v, t;
        if (bid < 1024)      { src = w1; dh = W1th; dl = W1tl; KS32v = 64; t = bid; }
        else if (bid < 2048) { src = w2; dh = W2th; dl = W2tl; KS32v = 64; t = bid - 1024; }
        else                 { src = w0; dh = W0th; dl = W0tl; KS32v = 8;  t = bid - 2048; }
        const int k0 = (t >> 5) * 64;
        const int n0 = (t & 31) * 64;
        {   // Phase A: 64(k) x 64(n) fp32 tile -> LDS, float4 row writes
            const int r  = tid >> 2;
            const int cb = (tid & 3) * 16;
            const float* p = src + (size_t)(k0 + r) * 2048 + n0 + cb;
#pragma unroll
            for (int q = 0; q < 4; ++q)
                *(float4*)&lfs[r * 68 + cb + q * 4] = *(const float4*)(p + q * 4);
        }
        __syncthreads();
        {   // Phase B: per-col gather 16 k's, split, write packed frags
            const int c  = tid >> 2;
            const int kq = tid & 3;
            ushort_t hb[16], lb[16];
#pragma unroll
            for (int j = 0; j < 16; ++j)
                split1(lfs[(kq * 16 + j) * 68 + c], hb[j], lb[j]);
            const int gn  = (n0 + c) >> 4;
            const int l16 = c & 15;
#pragma unroll
            for (int o = 0; o < 2; ++o) {
                const int koct  = (k0 >> 3) + kq * 2 + o;
                const int ks    = koct >> 2, koct3 = koct & 3;
                const size_t off = ((size_t)(gn * KS32v + ks) * 64 + l16 + (koct3 << 4)) * 8;
                uint4 v;
                v.x = (unsigned)hb[o*8+0] | ((unsigned)hb[o*8+1] << 16);
                v.y = (unsigned)hb[o*8+2] | ((unsigned)hb[o*8+3] << 16);
                v.z = (unsigned)hb[o*8+4] | ((unsigned)hb[o*8+5] << 16);
                v.w = (unsigned)hb[o*8+6] | ((unsigned)hb[o*8+7] << 16);
                *(uint4*)&dh[off] = v;
                v.x = (unsigned)lb[o*8+0] | ((unsigned)lb[o*8+1] << 16);
                v.y = (unsigned)lb[o*8+2] | ((unsigned)lb[o*8+3] << 16);
                v.z = (unsigned)lb[o*8+4] | ((unsigned)lb[o*8+5] << 16);
                v.w = (unsigned)lb[o*8+6] | ((unsigned)lb[o*8+7] << 16);
                *(uint4*)&dl[off] = v;
            }
        }
    } else if (bid < 2192) {
        // z split+pack: idx -> row r, 16 k's. KS32=8.
        const int idx = (bid - 2176) * 256 + tid;   // 0..4095
        const int r = idx >> 4, kq = idx & 15;
        const float* p = z + (size_t)r * 256 + kq * 16;
        float fv[16];
#pragma unroll
        for (int q = 0; q < 4; ++q) {
            float4 v = *(const float4*)(p + q * 4);
            fv[q * 4 + 0] = v.x; fv[q * 4 + 1] = v.y;
            fv[q * 4 + 2] = v.z; fv[q * 4 + 3] = v.w;
        }
        ushort_t hb[16], lb[16];
#pragma unroll
        for (int j = 0; j < 16; ++j) split1(fv[j], hb[j], lb[j]);
        const int gm = r >> 4, l16 = r & 15;
#pragma unroll
        for (int o = 0; o < 2; ++o) {
            const int koct = kq * 2 + o;
            const int ks = koct >> 2, koct3 = koct & 3;
            const size_t off = ((size_t)(gm * 8 + ks) * 64 + l16 + (koct3 << 4)) * 8;
            uint4 v;
            v.x = (unsigned)hb[o*8+0] | ((unsigned)hb[o*8+1] << 16);
            v.y = (unsigned)hb[o*8+2] | ((unsigned)hb[o*8+3] << 16);
            v.z = (unsigned)hb[o*8+4] | ((unsigned)hb[o*8+5] << 16);
            v.w = (unsigned)hb[o*8+6] | ((unsigned)hb[o*8+7] << 16);
            *(uint4*)&zh[off] = v;
            v.x = (unsigned)lb[o*8+0] | ((unsigned)lb[o*8+1] << 16);
            v.y = (unsigned)lb[o*8+2] | ((unsigned)lb[o*8+3] << 16);
            v.z = (unsigned)lb[o*8+4] | ((unsigned)lb[o*8+5] << 16);
            v.w = (unsigned)lb[o*8+6] | ((unsigned)lb[o*8+7] << 16);
            *(uint4*)&zl[off] = v;
        }
    } else {
        // fused head weights: one column per block
        const int k = bid - 2192;
        const float* W; const float* B; int off, card;
        if (k < 4)        { W = cw0; B = cb0; off = 0;   card = 4;   }
        else if (k < 20)  { W = cw1; B = cb1; off = 4;   card = 16;  }
        else if (k < 148) { W = cw2; B = cb2; off = 20;  card = 128; }
        else              { W = nw;  B = nbv; off = 148; card = 2;   }
        const int kc = k - off;
        float part[INCv + 1];
#pragma unroll
        for (int c = 0; c <= INCv; ++c) part[c] = 0.f;
#pragma unroll
        for (int it = 0; it < 2; ++it) {
            const int h = tid + it * 256;
            const float wv = W[h * card + kc];
#pragma unroll
            for (int c = 0; c < INCv; ++c) part[c] += cvw[h * INCv + c] * wv;
            part[INCv] += cvb[h] * wv;
        }
        __shared__ float red[INCv + 1][4];
        const int lane = tid & 63, wave = tid >> 6;
#pragma unroll
        for (int c = 0; c <= INCv; ++c) {
            float v = part[c];
#pragma unroll
            for (int o = 32; o >= 1; o >>= 1) v += __shfl_down(v, o, 64);
            if (lane == 0) red[c][wave] = v;
        }
        __syncthreads();
        if (tid <= INCv) {
            const float s = red[tid][0] + red[tid][1] + red[tid][2] + red[tid][3];
            if (tid < INCv) Mf[tid * NCOLS + k] = s;
            else            beta[k] = s + B[kc];
        }
    }
}

// ---------------------------------------------------------------------------
// Packed-operand MFMA GEMM, async global_load_lds staging, DOUBLE-BUFFERED
// with counted vmcnt + raw s_barrier (T3/T4 minimum-2-phase template):
// stage t+1's 6 per-thread DMA loads stay in flight across the barrier;
// vmcnt(6) waits only for stage t.  8 waves (4wr x 2wc), BM=128, BN=64,
// BK=64 per step, wave tile 32x32.  acc = ah*bh + (ah*bl + al*bh)/4096.
// OUT=0: fp32 partial at part + bz*524288.
// OUT=1: bias+relu+split PACKED to oH/oL (next layer's A, KS32_next=64).
// ---------------------------------------------------------------------------
template <int OUT>
__global__ __launch_bounds__(512, 4) void gemm_pk(
    const ushort_t* __restrict__ Ah, const ushort_t* __restrict__ Al,
    const ushort_t* __restrict__ Bh, const ushort_t* __restrict__ Bl,
    const float* __restrict__ bias, float* __restrict__ part,
    ushort_t* __restrict__ oH, ushort_t* __restrict__ oL,
    int KS32, int kchunk32, int steps)
{
    __shared__ ushort_t sAh[2][8192];
    __shared__ ushort_t sAl[2][8192];
    __shared__ ushort_t sBh[2][4096];
    __shared__ ushort_t sBl[2][4096];

    const int tid  = threadIdx.x;
    const int lane = tid & 63, w = tid >> 6;
    const int wr   = w >> 1, wc = w & 1;
    const int bx   = blockIdx.x, by = blockIdx.y, bz = blockIdx.z;
    const int kb0  = bz * kchunk32;

    f32x4 accH[2][2], accC[2][2];
#pragma unroll
    for (int r = 0; r < 2; ++r)
#pragma unroll
        for (int c = 0; c < 2; ++c) {
            accH[r][c] = (f32x4){0.f, 0.f, 0.f, 0.f};
            accC[r][c] = (f32x4){0.f, 0.f, 0.f, 0.f};
        }

    // ---- prologue: stage step 0 into buf 0 (6 DMA loads / thread) ----
    {
        const int kb = kb0;
#pragma unroll
        for (int i = 0; i < 2; ++i) {
            const int run = w + i * 8;
            const int g = run >> 1, ks = run & 1;
            const size_t f = ((size_t)(by * 8 + g) * KS32 + kb + ks) * 512 + lane * 8;
            gl_lds16(Ah + f, &sAh[0][run * 512]);
            gl_lds16(Al + f, &sAl[0][run * 512]);
        }
        const int g = w >> 1, ks = w & 1;
        const size_t f = ((size_t)(bx * 4 + g) * KS32 + kb + ks) * 512 + lane * 8;
        gl_lds16(Bh + f, &sBh[0][w * 512]);
        gl_lds16(Bl + f, &sBl[0][w * 512]);
    }

    for (int t = 0; t < steps; ++t) {
        const int cur = t & 1;
        const int nxt = t + 1;
        if (nxt < steps) {
            const int kb = kb0 + nxt * 2;
            const int nb = nxt & 1;
#pragma unroll
            for (int i = 0; i < 2; ++i) {
                const int run = w + i * 8;
                const int g = run >> 1, ks = run & 1;
                const size_t f = ((size_t)(by * 8 + g) * KS32 + kb + ks) * 512 + lane * 8;
                gl_lds16(Ah + f, &sAh[nb][run * 512]);
                gl_lds16(Al + f, &sAl[nb][run * 512]);
            }
            const int g = w >> 1, ks = w & 1;
            const size_t f = ((size_t)(bx * 4 + g) * KS32 + kb + ks) * 512 + lane * 8;
            gl_lds16(Bh + f, &sBh[nb][w * 512]);
            gl_lds16(Bl + f, &sBl[nb][w * 512]);
            asm volatile("s_waitcnt vmcnt(6)" ::: "memory");   // stage t done; t+1 in flight
        } else {
            asm volatile("s_waitcnt vmcnt(0)" ::: "memory");
        }
        __builtin_amdgcn_s_barrier();

        // ---- MFMA over the two k32 slices of buf[cur] ----
#pragma unroll
        for (int ks = 0; ks < 2; ++ks) {
            f16x8 aH[2], aL[2], bHf[2], bLf[2];
#pragma unroll
            for (int r = 0; r < 2; ++r) {
                const int off = (((wr * 2 + r) * 2 + ks) * 64 + lane) * 8;
                aH[r] = *(const f16x8*)&sAh[cur][off];
                aL[r] = *(const f16x8*)&sAl[cur][off];
            }
#pragma unroll
            for (int c = 0; c < 2; ++c) {
                const int off = (((wc * 2 + c) * 2 + ks) * 64 + lane) * 8;
                bHf[c] = *(const f16x8*)&sBh[cur][off];
                bLf[c] = *(const f16x8*)&sBl[cur][off];
            }
#pragma unroll
            for (int r = 0; r < 2; ++r)
#pragma unroll
                for (int c = 0; c < 2; ++c) {
                    accH[r][c] = __builtin_amdgcn_mfma_f32_16x16x32_f16(aH[r], bHf[c], accH[r][c], 0, 0, 0);
                    accC[r][c] = __builtin_amdgcn_mfma_f32_16x16x32_f16(aH[r], bLf[c], accC[r][c], 0, 0, 0);
                    accC[r][c] = __builtin_amdgcn_mfma_f32_16x16x32_f16(aL[r], bHf[c], accC[r][c], 0, 0, 0);
                }
        }
        __builtin_amdgcn_s_barrier();   // reads done before buf[cur] re-staged
    }

    const float inv = 1.f / 4096.f;
#pragma unroll
    for (int r = 0; r < 2; ++r)
#pragma unroll
        for (int c = 0; c < 2; ++c) {
            const int row0 = by * 128 + (wr * 2 + r) * 16 + ((lane >> 4) << 2);
            const int col  = bx * 64  + (wc * 2 + c) * 16 + (lane & 15);
            if (OUT == 0) {
                float* po = part + (size_t)bz * 524288;
#pragma unroll
                for (int e = 0; e < 4; ++e)
                    po[(size_t)(row0 + e) * 2048 + col] = accH[r][c][e] + accC[r][c][e] * inv;
            } else {
                const float vb = bias[col];
                const int gm = (by * 8 + wr * 2 + r);
                const int ks = col >> 5, koct3 = (col >> 3) & 3, j = col & 7;
                const size_t fb = ((size_t)(gm * 64 + ks) * 64) * 8 + (koct3 << 4) * 8 + j;
#pragma unroll
                for (int e = 0; e < 4; ++e) {
                    const float v = fmaxf(accH[r][c][e] + accC[r][c][e] * inv + vb, 0.f);
                    ushort_t h, l;
                    split1(v, h, l);
                    const int l16 = ((lane >> 4) << 2) + e;
                    oH[fb + (size_t)l16 * 8] = h;
                    oL[fb + (size_t)l16 * 8] = l;
                }
            }
        }
}

// ---------------------------------------------------------------------------
// Reduce 4 partials + bias + relu -> packed fp16 pairs (next layer's A).
// ---------------------------------------------------------------------------
__global__ __launch_bounds__(256) void reduce_pk(
    const float* __restrict__ part, const float* __restrict__ bias,
    ushort_t* __restrict__ oH, ushort_t* __restrict__ oL)
{
    const int b  = blockIdx.x;        // 512 blocks
    const int ct = b & 15, rg = b >> 4;
    const int e  = threadIdx.x * 4;
    const int row = rg * 8 + (e >> 7);
    const int col = ct * 128 + (e & 127);
    const size_t idx = (size_t)row * 2048 + col;
    float4 s = *(const float4*)&bias[col];
#pragma unroll
    for (int k = 0; k < 4; ++k) {
        const float4 p = *(const float4*)&part[(size_t)k * 524288 + idx];
        s.x += p.x; s.y += p.y; s.z += p.z; s.w += p.w;
    }
    s.x = fmaxf(s.x, 0.f); s.y = fmaxf(s.y, 0.f);
    s.z = fmaxf(s.z, 0.f); s.w = fmaxf(s.w, 0.f);
    ushort_t h[4], l[4];
    split1(s.x, h[0], l[0]); split1(s.y, h[1], l[1]);
    split1(s.z, h[2], l[2]); split1(s.w, h[3], l[3]);
    const int gm = row >> 4, l16 = row & 15;
    const int ks = col >> 5, koct3 = (col >> 3) & 3, j = col & 7;
    const size_t off = ((size_t)(gm * 64 + ks) * 64 + l16 + (koct3 << 4)) * 8 + j;
    ushort4 hv = {h[0], h[1], h[2], h[3]};
    ushort4 lv = {l[0], l[1], l[2], l[3]};
    *(ushort4*)&oH[off] = hv;
    *(ushort4*)&oL[off] = lv;
}

// ---------------------------------------------------------------------------
// Heads with INLINE layer-2 reduction: rv[c] = relu(b2[col] + sum_k part[k]).
// Each rh2 element is consumed by exactly one head thread, so no reduce2
// kernel / rh2 round-trip is needed.  bx<96 -> cat, bx>=96 -> num.
// ---------------------------------------------------------------------------
__global__ __launch_bounds__(256) void heads_kernel(
    const float* __restrict__ part, const float* __restrict__ b2,
    const float* __restrict__ Mf, const float* __restrict__ beta,
    const int* __restrict__ cat_target, const float* __restrict__ num_target,
    float* __restrict__ out)
{
    const int bx  = blockIdx.x;
    const int tid = threadIdx.x;
    __shared__ float Ms[INCv][128];
    __shared__ float Bsh[128];
    if (bx < 96) {
        const int g = bx >> 5;
        const int card = (g == 0) ? 4 : (g == 1) ? 16 : 128;
        const int off  = (g == 0) ? 0 : (g == 1) ? 4  : 20;
        for (int i = tid; i < card * INCv; i += 256) {
            int c = i / card, k = i % card;
            Ms[c][k] = Mf[c * NCOLS + off + k];
        }
        for (int i = tid; i < card; i += 256) Bsh[i] = beta[off + i];
        __syncthreads();

        const int idx = (bx & 31) * 256 + tid;
        const int n = idx >> 5, j = idx & 31;
        const int ci = g * 32 + j;
        const int l  = ci * 2;
        float rv[INCv];
#pragma unroll
        for (int c = 0; c < INCv; ++c) {
            const size_t e = (size_t)n * MLPHv + c * LL + l;
            float s = b2[c * LL + l];
#pragma unroll
            for (int k = 0; k < 4; ++k) s += part[(size_t)k * 524288 + e];
            rv[c] = fmaxf(s, 0.f);
        }

        float mx = -1e30f; int arg = 0;
        for (int k = 0; k < card; ++k) {
            float s = Bsh[k];
#pragma unroll
            for (int c = 0; c < INCv; ++c) s += rv[c] * Ms[c][k];
            if (s > mx) { mx = s; arg = k; }
        }
        const int tg = cat_target[n * 96 + ci];
        float sum = 0.f, stg = 0.f;
        for (int k = 0; k < card; ++k) {
            float s = Bsh[k];
#pragma unroll
            for (int c = 0; c < INCv; ++c) s += rv[c] * Ms[c][k];
            sum += expf(s - mx);
            if (k == tg) stg = s;
        }
        const float lse = mx + logf(sum);
        out[NN * LL * 3 + n * 96 + ci] = lse - stg;
        float* u = out + (size_t)(n * LL + l) * 3;
        u[0] = (float)arg; u[1] = 0.f; u[2] = 0.f;
    } else {
        const int idx = (bx - 96) * 256 + tid;  // 0..40959
        const int n = idx / 160, ni = idx % 160;
        const int l = (ni < 96) ? (2 * ni + 1) : (96 + ni);
        float rv[INCv];
#pragma unroll
        for (int c = 0; c < INCv; ++c) {
            const size_t e = (size_t)n * MLPHv + c * LL + l;
            float s = b2[c * LL + l];
#pragma unroll
            for (int k = 0; k < 4; ++k) s += part[(size_t)k * 524288 + e];
            rv[c] = fmaxf(s, 0.f);
        }
        float p0 = beta[148], p1 = beta[149];
#pragma unroll
        for (int c = 0; c < INCv; ++c) {
            p0 += rv[c] * Mf[c * NCOLS + 148];
            p1 += rv[c] * Mf[c * NCOLS + 149];
        }
        const float mu = 1.f / (1.f + expf(-p0));
        const float sp = (p1 > 20.f) ? p1 : log1pf(expf(p1));
        const float s  = sp + 1e-4f;
        const float hb = 1.f / 198.f;
        const float t  = num_target[n * 160 + ni];
        const float cp = 1.f / (1.f + expf(-((t + hb - mu) / s)));
        const float cm = 1.f / (1.f + expf(-((t - hb - mu) / s)));
        const float prob = (t < hb) ? cp : ((t > 1.f - hb) ? (1.f - cm) : (cp - cm));
        out[NN * LL * 3 + NN * 96 + n * 160 + ni] = -logf(fmaxf(prob, 1e-7f));
        float* u = out + (size_t)(n * LL + l) * 3;
        u[0] = 0.f; u[1] = rintf(mu * 99.f) / 99.f; u[2] = 0.f;
    }
}

// ---------------------------------------------------------------------------
extern "C" void kernel_launch(void* const* d_in, const int* in_sizes, int n_in,
                              void* d_out, int out_size, void* d_ws, size_t ws_size,
                              hipStream_t stream)
{
    const float* z   = (const float*)d_in[0];
    const float* w0  = (const float*)d_in[1];
    const float* b0  = (const float*)d_in[2];
    const float* w1  = (const float*)d_in[3];
    const float* b1  = (const float*)d_in[4];
    const float* w2  = (const float*)d_in[5];
    const float* b2  = (const float*)d_in[6];
    const float* cvw = (const float*)d_in[7];
    const float* cvb = (const float*)d_in[8];
    const float* cw0 = (const float*)d_in[9];
    const float* cb0 = (const float*)d_in[10];
    const float* cw1 = (const float*)d_in[11];
    const float* cb1 = (const float*)d_in[12];
    const float* cw2 = (const float*)d_in[13];
    const float* cb2 = (const float*)d_in[14];
    const float* nw  = (const float*)d_in[15];
    const float* nb  = (const float*)d_in[16];
    const float* num_target = (const float*)d_in[17];
    const int*   cat_target = (const int*)d_in[18];
    float* out = (float*)d_out;
    float* ws  = (float*)d_ws;

    size_t o = 0;
    float*    part = ws + o;                o += 4ull * 524288;   // 8 MB
    float*    Mf   = ws + o;                o += 1536;
    float*    beta = ws + o;                o += 256;
    ushort_t* zh   = (ushort_t*)(ws + o);   o += 32768;           // packed 256x256
    ushort_t* zl   = (ushort_t*)(ws + o);   o += 32768;
    ushort_t* r0h  = (ushort_t*)(ws + o);   o += 262144;          // packed 256x2048
    ushort_t* r0l  = (ushort_t*)(ws + o);   o += 262144;
    ushort_t* r1h  = (ushort_t*)(ws + o);   o += 262144;
    ushort_t* r1l  = (ushort_t*)(ws + o);   o += 262144;
    ushort_t* W0th = (ushort_t*)(ws + o);   o += 262144;          // packed 2048x256
    ushort_t* W0tl = (ushort_t*)(ws + o);   o += 262144;
    ushort_t* W1th = (ushort_t*)(ws + o);   o += 2097152;         // packed 2048x2048
    ushort_t* W1tl = (ushort_t*)(ws + o);   o += 2097152;
    ushort_t* W2th = (ushort_t*)(ws + o);   o += 2097152;
    ushort_t* W2tl = (ushort_t*)(ws + o);   o += 2097152;

    // 1. prep: W transpose+split+pack | z split+pack | head fusion
    prep_all<<<dim3(2342), 256, 0, stream>>>(
        z, w0, w1, w2, cvw, cvb, cw0, cb0, cw1, cb1, cw2, cb2, nw, nb,
        W0th, W0tl, W1th, W1tl, W2th, W2tl, zh, zl, Mf, beta);

    // 2. layer 0 (K=256, full-K): r0 = pack(relu(z@w0+b0))
    gemm_pk<1><<<dim3(32, 2, 1), 512, 0, stream>>>(
        zh, zl, W0th, W0tl, b0, nullptr, r0h, r0l, 8, 8, 4);

    // 3-4. layer 1 (K=2048, splitK=4) + reduce -> r1 packed
    gemm_pk<0><<<dim3(32, 2, 4), 512, 0, stream>>>(
        r0h, r0l, W1th, W1tl, nullptr, part, nullptr, nullptr, 64, 16, 8);
    reduce_pk<<<dim3(512), 256, 0, stream>>>(part, b1, r1h, r1l);

    // 5. layer 2 (K=2048, splitK=4) -> partials (reduced inline by heads)
    gemm_pk<0><<<dim3(32, 2, 4), 512, 0, stream>>>(
        r1h, r1l, W2th, W2tl, nullptr, part, nullptr, nullptr, 64, 16, 8);

    // 6. heads (inline 4-partial reduce + bias + relu)
    heads_kernel<<<dim3(256), 256, 0, stream>>>(
        part, b2, Mf, beta, cat_target, num_target, out);
}

// Round 12
// 73.727 us; speedup vs baseline: 13.1022x; 1.0554x over previous
//
#include <hip/hip_runtime.h>
#include <hip/hip_fp16.h>
#include <math.h>

#define NN   256
#define LL   256
#define HH   512
#define MLPHv 2048
#define INCv 8
#define NCOLS 150

typedef _Float16 f16x8 __attribute__((ext_vector_type(8)));
typedef float    f32x4 __attribute__((ext_vector_type(4)));
typedef unsigned short ushort_t;

// ---------------------------------------------------------------------------
// fp32 -> fp16 hi/lo split:  a ≈ hi + lo/4096, |residual| <= 2^-22 |a|.
// ---------------------------------------------------------------------------
__device__ __forceinline__ void split1(float f, ushort_t& h, ushort_t& l)
{
    __half hh = __float2half_rn(f);
    h = __half_as_ushort(hh);
    l = __half_as_ushort(__float2half_rn((f - __half2float(hh)) * 4096.f));
}

__device__ __forceinline__ void pack8(const float* fv, uint4& hv, uint4& lv)
{
    ushort_t h[8], l[8];
#pragma unroll
    for (int j = 0; j < 8; ++j) split1(fv[j], h[j], l[j]);
    hv.x = (unsigned)h[0] | ((unsigned)h[1] << 16);
    hv.y = (unsigned)h[2] | ((unsigned)h[3] << 16);
    hv.z = (unsigned)h[4] | ((unsigned)h[5] << 16);
    hv.w = (unsigned)h[6] | ((unsigned)h[7] << 16);
    lv.x = (unsigned)l[0] | ((unsigned)l[1] << 16);
    lv.y = (unsigned)l[2] | ((unsigned)l[3] << 16);
    lv.z = (unsigned)l[4] | ((unsigned)l[5] << 16);
    lv.w = (unsigned)l[6] | ((unsigned)l[7] << 16);
}

// async global->LDS 16B per lane (linear dest: wave-uniform base + lane*16).
typedef __attribute__((address_space(3))) unsigned int lds_u32;
typedef __attribute__((address_space(1))) const unsigned int glb_u32;
__device__ __forceinline__ void gl_lds16(const ushort_t* g, ushort_t* l)
{
    __builtin_amdgcn_global_load_lds((glb_u32*)g, (lds_u32*)l, 16, 0, 0);
}
__device__ __forceinline__ void gl_lds16f(const float* g, float* l)
{
    __builtin_amdgcn_global_load_lds((glb_u32*)g, (lds_u32*)l, 16, 0, 0);
}

// Fragment-linear packing (R10/R11-proven): X[row][k] lives at
// ((g*KS32 + ks)*64 + lane)*8 + j,  g=row>>4, ks=k>>5,
// lane=(row&15)+16*((k>>3)&3), j=k&7.

// ---------------------------------------------------------------------------
// prep_small: bid<16 -> z split+pack; else -> fused head weights (150 cols).
// (W pre-split eliminated: W is converted inside the GEMM now.)
// ---------------------------------------------------------------------------
__global__ __launch_bounds__(256) void prep_small(
    const float* __restrict__ z,
    const float* __restrict__ cvw, const float* __restrict__ cvb,
    const float* __restrict__ cw0, const float* __restrict__ cb0,
    const float* __restrict__ cw1, const float* __restrict__ cb1,
    const float* __restrict__ cw2, const float* __restrict__ cb2,
    const float* __restrict__ nw,  const float* __restrict__ nbv,
    ushort_t* __restrict__ zh, ushort_t* __restrict__ zl,
    float* __restrict__ Mf, float* __restrict__ beta)
{
    const int bid = blockIdx.x;
    const int tid = threadIdx.x;
    if (bid < 16) {
        // z split+pack: idx -> row r, 16 k's. KS32=8.
        const int idx = bid * 256 + tid;            // 0..4095
        const int r = idx >> 4, kq = idx & 15;
        const float* p = z + (size_t)r * 256 + kq * 16;
        float fv[16];
#pragma unroll
        for (int q = 0; q < 4; ++q) {
            float4 v = *(const float4*)(p + q * 4);
            fv[q * 4 + 0] = v.x; fv[q * 4 + 1] = v.y;
            fv[q * 4 + 2] = v.z; fv[q * 4 + 3] = v.w;
        }
        const int gm = r >> 4, l16 = r & 15;
#pragma unroll
        for (int o = 0; o < 2; ++o) {
            uint4 hv, lv;
            pack8(&fv[o * 8], hv, lv);
            const int koct = kq * 2 + o;
            const int ks = koct >> 2, koct3 = koct & 3;
            const size_t off = ((size_t)(gm * 8 + ks) * 64 + l16 + (koct3 << 4)) * 8;
            *(uint4*)&zh[off] = hv;
            *(uint4*)&zl[off] = lv;
        }
    } else {
        // fused head weights: one column per block
        const int k = bid - 16;
        const float* W; const float* B; int off, card;
        if (k < 4)        { W = cw0; B = cb0; off = 0;   card = 4;   }
        else if (k < 20)  { W = cw1; B = cb1; off = 4;   card = 16;  }
        else if (k < 148) { W = cw2; B = cb2; off = 20;  card = 128; }
        else              { W = nw;  B = nbv; off = 148; card = 2;   }
        const int kc = k - off;
        float part[INCv + 1];
#pragma unroll
        for (int c = 0; c <= INCv; ++c) part[c] = 0.f;
#pragma unroll
        for (int it = 0; it < 2; ++it) {
            const int h = tid + it * 256;
            const float wv = W[h * card + kc];
#pragma unroll
            for (int c = 0; c < INCv; ++c) part[c] += cvw[h * INCv + c] * wv;
            part[INCv] += cvb[h] * wv;
        }
        __shared__ float red[INCv + 1][4];
        const int lane = tid & 63, wave = tid >> 6;
#pragma unroll
        for (int c = 0; c <= INCv; ++c) {
            float v = part[c];
#pragma unroll
            for (int o = 32; o >= 1; o >>= 1) v += __shfl_down(v, o, 64);
            if (lane == 0) red[c][wave] = v;
        }
        __syncthreads();
        if (tid <= INCv) {
            const float s = red[tid][0] + red[tid][1] + red[tid][2] + red[tid][3];
            if (tid < INCv) Mf[tid * NCOLS + k] = s;
            else            beta[k] = s + B[kc];
        }
    }
}

// ---------------------------------------------------------------------------
// MFMA GEMM, A = packed fp16 pairs (DMA-staged), W = RAW fp32 rows
// (DMA-staged into padded LDS, then converted cooperatively per step):
//   stage t+1 (6 DMA/thread) -> vmcnt(6) -> barrier
//   -> convert: 8 fp32 reads (2-way free) + split + 2x b128 packed writes
//   -> lgkmcnt(0) -> barrier -> MFMA (R11-verbatim frag reads) -> barrier
// 8 waves (4wr x 2wc), BM=128, BN=64, BK=64/step, wave tile 32x32.
// acc = ah*bh + (ah*bl + al*bh)/4096.  LDS 128.5 KB -> 1 block/CU.
// OUT=0: fp32 partial at part + bz*524288.
// OUT=1: bias+relu+split PACKED to oH/oL (next layer's A, KS32_next=64).
// ---------------------------------------------------------------------------
template <int OUT>
__global__ __launch_bounds__(512, 1) void gemm_wf(
    const ushort_t* __restrict__ Ah, const ushort_t* __restrict__ Al,
    const float* __restrict__ W, const float* __restrict__ bias,
    float* __restrict__ part, ushort_t* __restrict__ oH, ushort_t* __restrict__ oL,
    int KS32, int kchunk32, int steps)
{
    __shared__ ushort_t sAh[2][8192];   // packed A hi
    __shared__ ushort_t sAl[2][8192];   // packed A lo
    __shared__ float    sWf[2][4160];   // raw fp32 W: 16 issues x 260 floats (1024B+16B pad)
    __shared__ ushort_t sWh[2][4096];   // packed W hi (converted)
    __shared__ ushort_t sWl[2][4096];   // packed W lo

    const int tid  = threadIdx.x;
    const int lane = tid & 63, w = tid >> 6;
    const int wr   = w >> 1, wc = w & 1;
    const int bx   = blockIdx.x, by = blockIdx.y, bz = blockIdx.z;
    const int bn   = bx * 64;
    const int kb0  = bz * kchunk32;

    f32x4 accH[2][2], accC[2][2];
#pragma unroll
    for (int r = 0; r < 2; ++r)
#pragma unroll
        for (int c = 0; c < 2; ++c) {
            accH[r][c] = (f32x4){0.f, 0.f, 0.f, 0.f};
            accC[r][c] = (f32x4){0.f, 0.f, 0.f, 0.f};
        }

    auto STAGE = [&](int ts, int b) {
        const int kb = kb0 + ts * 2;
        // A packed: 4 DMA issues/thread
#pragma unroll
        for (int i = 0; i < 2; ++i) {
            const int run = w + i * 8;
            const int g = run >> 1, ks = run & 1;
            const size_t f = ((size_t)(by * 8 + g) * KS32 + kb + ks) * 512 + lane * 8;
            gl_lds16(Ah + f, &sAh[b][run * 512]);
            gl_lds16(Al + f, &sAl[b][run * 512]);
        }
        // W fp32: 2 DMA issues/thread (issue i = 4 rows x 64 cols, 1KB)
        const int k0 = kb * 32;
#pragma unroll
        for (int ii = 0; ii < 2; ++ii) {
            const int i = w * 2 + ii;
            const float* src = W + (size_t)(k0 + i * 4 + (lane >> 4)) * 2048 + bn + (lane & 15) * 4;
            gl_lds16f(src, &sWf[b][i * 260]);
        }
    };

    STAGE(0, 0);
    for (int t = 0; t < steps; ++t) {
        const int cur = t & 1;
        if (t + 1 < steps) {
            STAGE(t + 1, cur ^ 1);
            asm volatile("s_waitcnt vmcnt(6)" ::: "memory");  // step t's 6 landed; t+1 in flight
        } else {
            asm volatile("s_waitcnt vmcnt(0)" ::: "memory");
        }
        __builtin_amdgcn_s_barrier();
        asm volatile("" ::: "memory");   // no LDS reads hoist above barrier

        // ---- convert phase: thread owns (col=lane, k-octet group=w) ----
        {
            const int col = lane;            // 0..63
            const int i0  = w * 2;           // fp32 issue pair for k rows w*8..w*8+7
            float fv[8];
#pragma unroll
            for (int j = 0; j < 4; ++j) fv[j]     = sWf[cur][i0 * 260 + j * 64 + col];
#pragma unroll
            for (int j = 0; j < 4; ++j) fv[4 + j] = sWf[cur][(i0 + 1) * 260 + j * 64 + col];
            uint4 hv, lv;
            pack8(fv, hv, lv);
            const int g = col >> 4, l16 = col & 15;
            const int ks = w >> 2, koct = w & 3;
            const int ub = ((g * 2 + ks) * 64 + l16 + koct * 16) * 8;
            *(uint4*)&sWh[cur][ub] = hv;
            *(uint4*)&sWl[cur][ub] = lv;
        }
        asm volatile("s_waitcnt lgkmcnt(0)" ::: "memory");   // my packed writes committed
        __builtin_amdgcn_s_barrier();
        asm volatile("" ::: "memory");   // no frag reads hoist above barrier

        // ---- MFMA over the two k32 slices (R11-verbatim) ----
#pragma unroll
        for (int ks = 0; ks < 2; ++ks) {
            f16x8 aH[2], aL[2], bHf[2], bLf[2];
#pragma unroll
            for (int r = 0; r < 2; ++r) {
                const int off = (((wr * 2 + r) * 2 + ks) * 64 + lane) * 8;
                aH[r] = *(const f16x8*)&sAh[cur][off];
                aL[r] = *(const f16x8*)&sAl[cur][off];
            }
#pragma unroll
            for (int c = 0; c < 2; ++c) {
                const int off = (((wc * 2 + c) * 2 + ks) * 64 + lane) * 8;
                bHf[c] = *(const f16x8*)&sWh[cur][off];
                bLf[c] = *(const f16x8*)&sWl[cur][off];
            }
#pragma unroll
            for (int r = 0; r < 2; ++r)
#pragma unroll
                for (int c = 0; c < 2; ++c) {
                    accH[r][c] = __builtin_amdgcn_mfma_f32_16x16x32_f16(aH[r], bHf[c], accH[r][c], 0, 0, 0);
                    accC[r][c] = __builtin_amdgcn_mfma_f32_16x16x32_f16(aH[r], bLf[c], accC[r][c], 0, 0, 0);
                    accC[r][c] = __builtin_amdgcn_mfma_f32_16x16x32_f16(aL[r], bHf[c], accC[r][c], 0, 0, 0);
                }
        }
        __builtin_amdgcn_s_barrier();    // all reads done before buffers re-staged
        asm volatile("" ::: "memory");
    }

    const float inv = 1.f / 4096.f;
#pragma unroll
    for (int r = 0; r < 2; ++r)
#pragma unroll
        for (int c = 0; c < 2; ++c) {
            const int row0 = by * 128 + (wr * 2 + r) * 16 + ((lane >> 4) << 2);
            const int col  = bn + (wc * 2 + c) * 16 + (lane & 15);
            if (OUT == 0) {
                float* po = part + (size_t)bz * 524288;
#pragma unroll
                for (int e = 0; e < 4; ++e)
                    po[(size_t)(row0 + e) * 2048 + col] = accH[r][c][e] + accC[r][c][e] * inv;
            } else {
                const float vb = bias[col];
                const int gm = (by * 8 + wr * 2 + r);
                const int ks = col >> 5, koct3 = (col >> 3) & 3, j = col & 7;
                const size_t fb = ((size_t)(gm * 64 + ks) * 64) * 8 + (koct3 << 4) * 8 + j;
#pragma unroll
                for (int e = 0; e < 4; ++e) {
                    const float v = fmaxf(accH[r][c][e] + accC[r][c][e] * inv + vb, 0.f);
                    ushort_t h, l;
                    split1(v, h, l);
                    const int l16 = ((lane >> 4) << 2) + e;
                    oH[fb + (size_t)l16 * 8] = h;
                    oL[fb + (size_t)l16 * 8] = l;
                }
            }
        }
}

// ---------------------------------------------------------------------------
// Reduce 4 partials + bias + relu -> packed fp16 pairs (next layer's A).
// ---------------------------------------------------------------------------
__global__ __launch_bounds__(256) void reduce_pk(
    const float* __restrict__ part, const float* __restrict__ bias,
    ushort_t* __restrict__ oH, ushort_t* __restrict__ oL)
{
    const int b  = blockIdx.x;        // 512 blocks
    const int ct = b & 15, rg = b >> 4;
    const int e  = threadIdx.x * 4;
    const int row = rg * 8 + (e >> 7);
    const int col = ct * 128 + (e & 127);
    const size_t idx = (size_t)row * 2048 + col;
    float4 s = *(const float4*)&bias[col];
#pragma unroll
    for (int k = 0; k < 4; ++k) {
        const float4 p = *(const float4*)&part[(size_t)k * 524288 + idx];
        s.x += p.x; s.y += p.y; s.z += p.z; s.w += p.w;
    }
    s.x = fmaxf(s.x, 0.f); s.y = fmaxf(s.y, 0.f);
    s.z = fmaxf(s.z, 0.f); s.w = fmaxf(s.w, 0.f);
    ushort_t h[4], l[4];
    split1(s.x, h[0], l[0]); split1(s.y, h[1], l[1]);
    split1(s.z, h[2], l[2]); split1(s.w, h[3], l[3]);
    const int gm = row >> 4, l16 = row & 15;
    const int ks = col >> 5, koct3 = (col >> 3) & 3, j = col & 7;
    const size_t off = ((size_t)(gm * 64 + ks) * 64 + l16 + (koct3 << 4)) * 8 + j;
    ushort4 hv = {h[0], h[1], h[2], h[3]};
    ushort4 lv = {l[0], l[1], l[2], l[3]};
    *(ushort4*)&oH[off] = hv;
    *(ushort4*)&oL[off] = lv;
}

// ---------------------------------------------------------------------------
// Heads with INLINE layer-2 reduction (R11-proven).
// ---------------------------------------------------------------------------
__global__ __launch_bounds__(256) void heads_kernel(
    const float* __restrict__ part, const float* __restrict__ b2,
    const float* __restrict__ Mf, const float* __restrict__ beta,
    const int* __restrict__ cat_target, const float* __restrict__ num_target,
    float* __restrict__ out)
{
    const int bx  = blockIdx.x;
    const int tid = threadIdx.x;
    __shared__ float Ms[INCv][128];
    __shared__ float Bsh[128];
    if (bx < 96) {
        const int g = bx >> 5;
        const int card = (g == 0) ? 4 : (g == 1) ? 16 : 128;
        const int off  = (g == 0) ? 0 : (g == 1) ? 4  : 20;
        for (int i = tid; i < card * INCv; i += 256) {
            int c = i / card, k = i % card;
            Ms[c][k] = Mf[c * NCOLS + off + k];
        }
        for (int i = tid; i < card; i += 256) Bsh[i] = beta[off + i];
        __syncthreads();

        const int idx = (bx & 31) * 256 + tid;
        const int n = idx >> 5, j = idx & 31;
        const int ci = g * 32 + j;
        const int l  = ci * 2;
        float rv[INCv];
#pragma unroll
        for (int c = 0; c < INCv; ++c) {
            const size_t e = (size_t)n * MLPHv + c * LL + l;
            float s = b2[c * LL + l];
#pragma unroll
            for (int k = 0; k < 4; ++k) s += part[(size_t)k * 524288 + e];
            rv[c] = fmaxf(s, 0.f);
        }

        float mx = -1e30f; int arg = 0;
        for (int k = 0; k < card; ++k) {
            float s = Bsh[k];
#pragma unroll
            for (int c = 0; c < INCv; ++c) s += rv[c] * Ms[c][k];
            if (s > mx) { mx = s; arg = k; }
        }
        const int tg = cat_target[n * 96 + ci];
        float sum = 0.f, stg = 0.f;
        for (int k = 0; k < card; ++k) {
            float s = Bsh[k];
#pragma unroll
            for (int c = 0; c < INCv; ++c) s += rv[c] * Ms[c][k];
            sum += expf(s - mx);
            if (k == tg) stg = s;
        }
        const float lse = mx + logf(sum);
        out[NN * LL * 3 + n * 96 + ci] = lse - stg;
        float* u = out + (size_t)(n * LL + l) * 3;
        u[0] = (float)arg; u[1] = 0.f; u[2] = 0.f;
    } else {
        const int idx = (bx - 96) * 256 + tid;  // 0..40959
        const int n = idx / 160, ni = idx % 160;
        const int l = (ni < 96) ? (2 * ni + 1) : (96 + ni);
        float rv[INCv];
#pragma unroll
        for (int c = 0; c < INCv; ++c) {
            const size_t e = (size_t)n * MLPHv + c * LL + l;
            float s = b2[c * LL + l];
#pragma unroll
            for (int k = 0; k < 4; ++k) s += part[(size_t)k * 524288 + e];
            rv[c] = fmaxf(s, 0.f);
        }
        float p0 = beta[148], p1 = beta[149];
#pragma unroll
        for (int c = 0; c < INCv; ++c) {
            p0 += rv[c] * Mf[c * NCOLS + 148];
            p1 += rv[c] * Mf[c * NCOLS + 149];
        }
        const float mu = 1.f / (1.f + expf(-p0));
        const float sp = (p1 > 20.f) ? p1 : log1pf(expf(p1));
        const float s  = sp + 1e-4f;
        const float hb = 1.f / 198.f;
        const float t  = num_target[n * 160 + ni];
        const float cp = 1.f / (1.f + expf(-((t + hb - mu) / s)));
        const float cm = 1.f / (1.f + expf(-((t - hb - mu) / s)));
        const float prob = (t < hb) ? cp : ((t > 1.f - hb) ? (1.f - cm) : (cp - cm));
        out[NN * LL * 3 + NN * 96 + n * 160 + ni] = -logf(fmaxf(prob, 1e-7f));
        float* u = out + (size_t)(n * LL + l) * 3;
        u[0] = 0.f; u[1] = rintf(mu * 99.f) / 99.f; u[2] = 0.f;
    }
}

// ---------------------------------------------------------------------------
extern "C" void kernel_launch(void* const* d_in, const int* in_sizes, int n_in,
                              void* d_out, int out_size, void* d_ws, size_t ws_size,
                              hipStream_t stream)
{
    const float* z   = (const float*)d_in[0];
    const float* w0  = (const float*)d_in[1];
    const float* b0  = (const float*)d_in[2];
    const float* w1  = (const float*)d_in[3];
    const float* b1  = (const float*)d_in[4];
    const float* w2  = (const float*)d_in[5];
    const float* b2  = (const float*)d_in[6];
    const float* cvw = (const float*)d_in[7];
    const float* cvb = (const float*)d_in[8];
    const float* cw0 = (const float*)d_in[9];
    const float* cb0 = (const float*)d_in[10];
    const float* cw1 = (const float*)d_in[11];
    const float* cb1 = (const float*)d_in[12];
    const float* cw2 = (const float*)d_in[13];
    const float* cb2 = (const float*)d_in[14];
    const float* nw  = (const float*)d_in[15];
    const float* nb  = (const float*)d_in[16];
    const float* num_target = (const float*)d_in[17];
    const int*   cat_target = (const int*)d_in[18];
    float* out = (float*)d_out;
    float* ws  = (float*)d_ws;

    size_t o = 0;
    float*    part = ws + o;                o += 4ull * 524288;   // 8 MB
    float*    Mf   = ws + o;                o += 1536;
    float*    beta = ws + o;                o += 256;
    ushort_t* zh   = (ushort_t*)(ws + o);   o += 32768;           // packed 256x256
    ushort_t* zl   = (ushort_t*)(ws + o);   o += 32768;
    ushort_t* r0h  = (ushort_t*)(ws + o);   o += 262144;          // packed 256x2048
    ushort_t* r0l  = (ushort_t*)(ws + o);   o += 262144;
    ushort_t* r1h  = (ushort_t*)(ws + o);   o += 262144;
    ushort_t* r1l  = (ushort_t*)(ws + o);   o += 262144;

    // 1. prep: z split+pack | head-weight fusion (W prep eliminated)
    prep_small<<<dim3(166), 256, 0, stream>>>(
        z, cvw, cvb, cw0, cb0, cw1, cb1, cw2, cb2, nw, nb, zh, zl, Mf, beta);

    // 2. layer 0 (K=256, full-K): r0 = pack(relu(z@w0+b0))
    gemm_wf<1><<<dim3(32, 2, 1), 512, 0, stream>>>(
        zh, zl, w0, b0, nullptr, r0h, r0l, 8, 8, 4);

    // 3-4. layer 1 (K=2048, splitK=4) + reduce -> r1 packed
    gemm_wf<0><<<dim3(32, 2, 4), 512, 0, stream>>>(
        r0h, r0l, w1, nullptr, part, nullptr, nullptr, 64, 16, 8);
    reduce_pk<<<dim3(512), 256, 0, stream>>>(part, b1, r1h, r1l);

    // 5. layer 2 (K=2048, splitK=4) -> partials (reduced inline by heads)
    gemm_wf<0><<<dim3(32, 2, 4), 512, 0, stream>>>(
        r1h, r1l, w2, nullptr, part, nullptr, nullptr, 64, 16, 8);

    // 6. heads (inline 4-partial reduce + bias + relu)
    heads_kernel<<<dim3(256), 256, 0, stream>>>(
        part, b2, Mf, beta, cat_target, num_target, out);
}

// Round 13
// 72.852 us; speedup vs baseline: 13.2596x; 1.0120x over previous
//
#include <hip/hip_runtime.h>
#include <hip/hip_fp16.h>
#include <math.h>

#define NN   256
#define LL   256
#define HH   512
#define MLPHv 2048
#define INCv 8
#define NCOLS 150

typedef _Float16 f16x8 __attribute__((ext_vector_type(8)));
typedef float    f32x4 __attribute__((ext_vector_type(4)));
typedef unsigned short ushort_t;

// ---------------------------------------------------------------------------
// fp32 -> fp16 hi/lo split:  a ≈ hi + lo/4096, |residual| <= 2^-22 |a|.
// ---------------------------------------------------------------------------
__device__ __forceinline__ void split1(float f, ushort_t& h, ushort_t& l)
{
    __half hh = __float2half_rn(f);
    h = __half_as_ushort(hh);
    l = __half_as_ushort(__float2half_rn((f - __half2float(hh)) * 4096.f));
}

__device__ __forceinline__ void pack8(const float* fv, uint4& hv, uint4& lv)
{
    ushort_t h[8], l[8];
#pragma unroll
    for (int j = 0; j < 8; ++j) split1(fv[j], h[j], l[j]);
    hv.x = (unsigned)h[0] | ((unsigned)h[1] << 16);
    hv.y = (unsigned)h[2] | ((unsigned)h[3] << 16);
    hv.z = (unsigned)h[4] | ((unsigned)h[5] << 16);
    hv.w = (unsigned)h[6] | ((unsigned)h[7] << 16);
    lv.x = (unsigned)l[0] | ((unsigned)l[1] << 16);
    lv.y = (unsigned)l[2] | ((unsigned)l[3] << 16);
    lv.z = (unsigned)l[4] | ((unsigned)l[5] << 16);
    lv.w = (unsigned)l[6] | ((unsigned)l[7] << 16);
}

// async global->LDS 16B per lane (linear dest: wave-uniform base + lane*16).
typedef __attribute__((address_space(3))) unsigned int lds_u32;
typedef __attribute__((address_space(1))) const unsigned int glb_u32;
__device__ __forceinline__ void gl_lds16(const ushort_t* g, ushort_t* l)
{
    __builtin_amdgcn_global_load_lds((glb_u32*)g, (lds_u32*)l, 16, 0, 0);
}
__device__ __forceinline__ void gl_lds16f(const float* g, float* l)
{
    __builtin_amdgcn_global_load_lds((glb_u32*)g, (lds_u32*)l, 16, 0, 0);
}

// Fragment-linear packing (R10-12 proven): X[row][k] lives at
// ((g*KS32 + ks)*64 + lane)*8 + j,  g=row>>4, ks=k>>5,
// lane=(row&15)+16*((k>>3)&3), j=k&7.

// ---------------------------------------------------------------------------
// prep_small: bid<16 -> z split+pack; else -> fused head weights (150 cols).
// ---------------------------------------------------------------------------
__global__ __launch_bounds__(256) void prep_small(
    const float* __restrict__ z,
    const float* __restrict__ cvw, const float* __restrict__ cvb,
    const float* __restrict__ cw0, const float* __restrict__ cb0,
    const float* __restrict__ cw1, const float* __restrict__ cb1,
    const float* __restrict__ cw2, const float* __restrict__ cb2,
    const float* __restrict__ nw,  const float* __restrict__ nbv,
    ushort_t* __restrict__ zh, ushort_t* __restrict__ zl,
    float* __restrict__ Mf, float* __restrict__ beta)
{
    const int bid = blockIdx.x;
    const int tid = threadIdx.x;
    if (bid < 16) {
        const int idx = bid * 256 + tid;            // 0..4095
        const int r = idx >> 4, kq = idx & 15;
        const float* p = z + (size_t)r * 256 + kq * 16;
        float fv[16];
#pragma unroll
        for (int q = 0; q < 4; ++q) {
            float4 v = *(const float4*)(p + q * 4);
            fv[q * 4 + 0] = v.x; fv[q * 4 + 1] = v.y;
            fv[q * 4 + 2] = v.z; fv[q * 4 + 3] = v.w;
        }
        const int gm = r >> 4, l16 = r & 15;
#pragma unroll
        for (int o = 0; o < 2; ++o) {
            uint4 hv, lv;
            pack8(&fv[o * 8], hv, lv);
            const int koct = kq * 2 + o;
            const int ks = koct >> 2, koct3 = koct & 3;
            const size_t off = ((size_t)(gm * 8 + ks) * 64 + l16 + (koct3 << 4)) * 8;
            *(uint4*)&zh[off] = hv;
            *(uint4*)&zl[off] = lv;
        }
    } else {
        const int k = bid - 16;
        const float* W; const float* B; int off, card;
        if (k < 4)        { W = cw0; B = cb0; off = 0;   card = 4;   }
        else if (k < 20)  { W = cw1; B = cb1; off = 4;   card = 16;  }
        else if (k < 148) { W = cw2; B = cb2; off = 20;  card = 128; }
        else              { W = nw;  B = nbv; off = 148; card = 2;   }
        const int kc = k - off;
        float part[INCv + 1];
#pragma unroll
        for (int c = 0; c <= INCv; ++c) part[c] = 0.f;
#pragma unroll
        for (int it = 0; it < 2; ++it) {
            const int h = tid + it * 256;
            const float wv = W[h * card + kc];
#pragma unroll
            for (int c = 0; c < INCv; ++c) part[c] += cvw[h * INCv + c] * wv;
            part[INCv] += cvb[h] * wv;
        }
        __shared__ float red[INCv + 1][4];
        const int lane = tid & 63, wave = tid >> 6;
#pragma unroll
        for (int c = 0; c <= INCv; ++c) {
            float v = part[c];
#pragma unroll
            for (int o = 32; o >= 1; o >>= 1) v += __shfl_down(v, o, 64);
            if (lane == 0) red[c][wave] = v;
        }
        __syncthreads();
        if (tid <= INCv) {
            const float s = red[tid][0] + red[tid][1] + red[tid][2] + red[tid][3];
            if (tid < INCv) Mf[tid * NCOLS + k] = s;
            else            beta[k] = s + B[kc];
        }
    }
}

// ---------------------------------------------------------------------------
// 1024-thread MFMA GEMM (16 waves = 4/SIMD), A = packed fp16 pairs (DMA),
// W = raw fp32 rows (DMA into padded LDS, converted cooperatively per step).
// Step: STAGE(t+1) [3 DMA/thread] -> vmcnt(3) -> barrier -> convert (4 fp32/
// thread -> single-buffered sWh/sWl) -> lgkmcnt(0) -> barrier -> MFMA ->
// barrier.  Wave grid 4wr x 4wc; wave tile 32x16 rows x cols; BM=128, BN=64,
// BK=64/step.  acc = ah*bh + (ah*bl + al*bh)/4096.  LDS ~113 KB.
// OUT=0: fp32 partial at part + bz*524288.
// OUT=1: bias+relu+split PACKED to oH/oL (next layer's A, KS32_next=64).
// ---------------------------------------------------------------------------
template <int OUT>
__global__ __launch_bounds__(1024, 1) void gemm_w2(
    const ushort_t* __restrict__ Ah, const ushort_t* __restrict__ Al,
    const float* __restrict__ W, const float* __restrict__ bias,
    float* __restrict__ part, ushort_t* __restrict__ oH, ushort_t* __restrict__ oL,
    int KS32, int kchunk32, int steps)
{
    __shared__ ushort_t sAh[2][8192];   // packed A hi (dbuf)
    __shared__ ushort_t sAl[2][8192];   // packed A lo (dbuf)
    __shared__ float    sWf[2][4160];   // raw fp32 W: 16 issues x 260 (dbuf)
    __shared__ ushort_t sWh[4096];      // packed W hi (single: made+used per step)
    __shared__ ushort_t sWl[4096];      // packed W lo

    const int tid  = threadIdx.x;
    const int lane = tid & 63, w = tid >> 6;        // wave 0..15
    const int wr   = w >> 2, wc = w & 3;            // 4 x 4 wave grid
    const int bx   = blockIdx.x, by = blockIdx.y, bz = blockIdx.z;
    const int bn   = bx * 64;
    const int kb0  = bz * kchunk32;

    f32x4 accH[2], accC[2];
#pragma unroll
    for (int r = 0; r < 2; ++r) {
        accH[r] = (f32x4){0.f, 0.f, 0.f, 0.f};
        accC[r] = (f32x4){0.f, 0.f, 0.f, 0.f};
    }

    auto STAGE = [&](int ts, int b) {
        const int kb = kb0 + ts * 2;
        // A: wave w stages run w (g = w>>1, ks = w&1), both planes (2 issues)
        const int g = w >> 1, ks = w & 1;
        const size_t fA = ((size_t)(by * 8 + g) * KS32 + kb + ks) * 512 + lane * 8;
        gl_lds16(Ah + fA, &sAh[b][w * 512]);
        gl_lds16(Al + fA, &sAl[b][w * 512]);
        // W fp32: wave w stages issue w (4 k-rows x 64 cols = 1KB)
        const int k0 = kb * 32;
        const float* src = W + (size_t)(k0 + w * 4 + (lane >> 4)) * 2048 + bn + (lane & 15) * 4;
        gl_lds16f(src, &sWf[b][w * 260]);
    };

    STAGE(0, 0);
    for (int t = 0; t < steps; ++t) {
        const int cur = t & 1;
        if (t + 1 < steps) {
            STAGE(t + 1, cur ^ 1);
            asm volatile("s_waitcnt vmcnt(3)" ::: "memory");  // step t landed; t+1 in flight
        } else {
            asm volatile("s_waitcnt vmcnt(0)" ::: "memory");
        }
        __builtin_amdgcn_s_barrier();
        asm volatile("" ::: "memory");

        // ---- convert: thread -> (col = tid&63, q = tid>>6), 4 fp32 ----
        {
            const int col = tid & 63;
            const int q   = tid >> 6;                 // 0..15 (== w)
            const int ks  = q >> 3, koct3 = (q >> 1) & 3, hf = q & 1;
            const int i   = ks * 8 + koct3 * 2 + hf;  // fp32 issue index
            float fv[4];
#pragma unroll
            for (int j = 0; j < 4; ++j) fv[j] = sWf[cur][i * 260 + j * 64 + col];
            ushort_t h[4], l[4];
#pragma unroll
            for (int j = 0; j < 4; ++j) split1(fv[j], h[j], l[j]);
            uint2 hv, lv;
            hv.x = (unsigned)h[0] | ((unsigned)h[1] << 16);
            hv.y = (unsigned)h[2] | ((unsigned)h[3] << 16);
            lv.x = (unsigned)l[0] | ((unsigned)l[1] << 16);
            lv.y = (unsigned)l[2] | ((unsigned)l[3] << 16);
            const int g2 = col >> 4, l16 = col & 15;
            const int ub = ((g2 * 2 + ks) * 64 + l16 + koct3 * 16) * 8 + hf * 4;
            *(uint2*)&sWh[ub] = hv;
            *(uint2*)&sWl[ub] = lv;
        }
        asm volatile("s_waitcnt lgkmcnt(0)" ::: "memory");
        __builtin_amdgcn_s_barrier();
        asm volatile("" ::: "memory");

        // ---- MFMA over the two k32 slices ----
#pragma unroll
        for (int ks = 0; ks < 2; ++ks) {
            f16x8 aH[2], aL[2], bHf, bLf;
#pragma unroll
            for (int r = 0; r < 2; ++r) {
                const int off = (((wr * 2 + r) * 2 + ks) * 64 + lane) * 8;
                aH[r] = *(const f16x8*)&sAh[cur][off];
                aL[r] = *(const f16x8*)&sAl[cur][off];
            }
            {
                const int off = ((wc * 2 + ks) * 64 + lane) * 8;
                bHf = *(const f16x8*)&sWh[off];
                bLf = *(const f16x8*)&sWl[off];
            }
#pragma unroll
            for (int r = 0; r < 2; ++r) {
                accH[r] = __builtin_amdgcn_mfma_f32_16x16x32_f16(aH[r], bHf, accH[r], 0, 0, 0);
                accC[r] = __builtin_amdgcn_mfma_f32_16x16x32_f16(aH[r], bLf, accC[r], 0, 0, 0);
                accC[r] = __builtin_amdgcn_mfma_f32_16x16x32_f16(aL[r], bHf, accC[r], 0, 0, 0);
            }
        }
        __builtin_amdgcn_s_barrier();   // reads done before next stage/convert
        asm volatile("" ::: "memory");
    }

    const float inv = 1.f / 4096.f;
#pragma unroll
    for (int r = 0; r < 2; ++r) {
        const int row0 = by * 128 + (wr * 2 + r) * 16 + ((lane >> 4) << 2);
        const int col  = bn + wc * 16 + (lane & 15);
        if (OUT == 0) {
            float* po = part + (size_t)bz * 524288;
#pragma unroll
            for (int e = 0; e < 4; ++e)
                po[(size_t)(row0 + e) * 2048 + col] = accH[r][e] + accC[r][e] * inv;
        } else {
            const float vb = bias[col];
            const int gm = by * 8 + wr * 2 + r;
            const int ks = col >> 5, koct3 = (col >> 3) & 3, j = col & 7;
            const size_t fb = ((size_t)(gm * 64 + ks) * 64) * 8 + (koct3 << 4) * 8 + j;
#pragma unroll
            for (int e = 0; e < 4; ++e) {
                const float v = fmaxf(accH[r][e] + accC[r][e] * inv + vb, 0.f);
                ushort_t h, l;
                split1(v, h, l);
                const int l16 = ((lane >> 4) << 2) + e;
                oH[fb + (size_t)l16 * 8] = h;
                oL[fb + (size_t)l16 * 8] = l;
            }
        }
    }
}

// ---------------------------------------------------------------------------
// Reduce 4 partials + bias + relu -> packed fp16 pairs (next layer's A).
// ---------------------------------------------------------------------------
__global__ __launch_bounds__(256) void reduce_pk(
    const float* __restrict__ part, const float* __restrict__ bias,
    ushort_t* __restrict__ oH, ushort_t* __restrict__ oL)
{
    const int b  = blockIdx.x;        // 512 blocks
    const int ct = b & 15, rg = b >> 4;
    const int e  = threadIdx.x * 4;
    const int row = rg * 8 + (e >> 7);
    const int col = ct * 128 + (e & 127);
    const size_t idx = (size_t)row * 2048 + col;
    float4 s = *(const float4*)&bias[col];
#pragma unroll
    for (int k = 0; k < 4; ++k) {
        const float4 p = *(const float4*)&part[(size_t)k * 524288 + idx];
        s.x += p.x; s.y += p.y; s.z += p.z; s.w += p.w;
    }
    s.x = fmaxf(s.x, 0.f); s.y = fmaxf(s.y, 0.f);
    s.z = fmaxf(s.z, 0.f); s.w = fmaxf(s.w, 0.f);
    ushort_t h[4], l[4];
    split1(s.x, h[0], l[0]); split1(s.y, h[1], l[1]);
    split1(s.z, h[2], l[2]); split1(s.w, h[3], l[3]);
    const int gm = row >> 4, l16 = row & 15;
    const int ks = col >> 5, koct3 = (col >> 3) & 3, j = col & 7;
    const size_t off = ((size_t)(gm * 64 + ks) * 64 + l16 + (koct3 << 4)) * 8 + j;
    ushort4 hv = {h[0], h[1], h[2], h[3]};
    ushort4 lv = {l[0], l[1], l[2], l[3]};
    *(ushort4*)&oH[off] = hv;
    *(ushort4*)&oL[off] = lv;
}

// ---------------------------------------------------------------------------
// Heads with INLINE layer-2 reduction (R11/R12-proven).
// ---------------------------------------------------------------------------
__global__ __launch_bounds__(256) void heads_kernel(
    const float* __restrict__ part, const float* __restrict__ b2,
    const float* __restrict__ Mf, const float* __restrict__ beta,
    const int* __restrict__ cat_target, const float* __restrict__ num_target,
    float* __restrict__ out)
{
    const int bx  = blockIdx.x;
    const int tid = threadIdx.x;
    __shared__ float Ms[INCv][128];
    __shared__ float Bsh[128];
    if (bx < 96) {
        const int g = bx >> 5;
        const int card = (g == 0) ? 4 : (g == 1) ? 16 : 128;
        const int off  = (g == 0) ? 0 : (g == 1) ? 4  : 20;
        for (int i = tid; i < card * INCv; i += 256) {
            int c = i / card, k = i % card;
            Ms[c][k] = Mf[c * NCOLS + off + k];
        }
        for (int i = tid; i < card; i += 256) Bsh[i] = beta[off + i];
        __syncthreads();

        const int idx = (bx & 31) * 256 + tid;
        const int n = idx >> 5, j = idx & 31;
        const int ci = g * 32 + j;
        const int l  = ci * 2;
        float rv[INCv];
#pragma unroll
        for (int c = 0; c < INCv; ++c) {
            const size_t e = (size_t)n * MLPHv + c * LL + l;
            float s = b2[c * LL + l];
#pragma unroll
            for (int k = 0; k < 4; ++k) s += part[(size_t)k * 524288 + e];
            rv[c] = fmaxf(s, 0.f);
        }

        float mx = -1e30f; int arg = 0;
        for (int k = 0; k < card; ++k) {
            float s = Bsh[k];
#pragma unroll
            for (int c = 0; c < INCv; ++c) s += rv[c] * Ms[c][k];
            if (s > mx) { mx = s; arg = k; }
        }
        const int tg = cat_target[n * 96 + ci];
        float sum = 0.f, stg = 0.f;
        for (int k = 0; k < card; ++k) {
            float s = Bsh[k];
#pragma unroll
            for (int c = 0; c < INCv; ++c) s += rv[c] * Ms[c][k];
            sum += expf(s - mx);
            if (k == tg) stg = s;
        }
        const float lse = mx + logf(sum);
        out[NN * LL * 3 + n * 96 + ci] = lse - stg;
        float* u = out + (size_t)(n * LL + l) * 3;
        u[0] = (float)arg; u[1] = 0.f; u[2] = 0.f;
    } else {
        const int idx = (bx - 96) * 256 + tid;  // 0..40959
        const int n = idx / 160, ni = idx % 160;
        const int l = (ni < 96) ? (2 * ni + 1) : (96 + ni);
        float rv[INCv];
#pragma unroll
        for (int c = 0; c < INCv; ++c) {
            const size_t e = (size_t)n * MLPHv + c * LL + l;
            float s = b2[c * LL + l];
#pragma unroll
            for (int k = 0; k < 4; ++k) s += part[(size_t)k * 524288 + e];
            rv[c] = fmaxf(s, 0.f);
        }
        float p0 = beta[148], p1 = beta[149];
#pragma unroll
        for (int c = 0; c < INCv; ++c) {
            p0 += rv[c] * Mf[c * NCOLS + 148];
            p1 += rv[c] * Mf[c * NCOLS + 149];
        }
        const float mu = 1.f / (1.f + expf(-p0));
        const float sp = (p1 > 20.f) ? p1 : log1pf(expf(p1));
        const float s  = sp + 1e-4f;
        const float hb = 1.f / 198.f;
        const float t  = num_target[n * 160 + ni];
        const float cp = 1.f / (1.f + expf(-((t + hb - mu) / s)));
        const float cm = 1.f / (1.f + expf(-((t - hb - mu) / s)));
        const float prob = (t < hb) ? cp : ((t > 1.f - hb) ? (1.f - cm) : (cp - cm));
        out[NN * LL * 3 + NN * 96 + n * 160 + ni] = -logf(fmaxf(prob, 1e-7f));
        float* u = out + (size_t)(n * LL + l) * 3;
        u[0] = 0.f; u[1] = rintf(mu * 99.f) / 99.f; u[2] = 0.f;
    }
}

// ---------------------------------------------------------------------------
extern "C" void kernel_launch(void* const* d_in, const int* in_sizes, int n_in,
                              void* d_out, int out_size, void* d_ws, size_t ws_size,
                              hipStream_t stream)
{
    const float* z   = (const float*)d_in[0];
    const float* w0  = (const float*)d_in[1];
    const float* b0  = (const float*)d_in[2];
    const float* w1  = (const float*)d_in[3];
    const float* b1  = (const float*)d_in[4];
    const float* w2  = (const float*)d_in[5];
    const float* b2  = (const float*)d_in[6];
    const float* cvw = (const float*)d_in[7];
    const float* cvb = (const float*)d_in[8];
    const float* cw0 = (const float*)d_in[9];
    const float* cb0 = (const float*)d_in[10];
    const float* cw1 = (const float*)d_in[11];
    const float* cb1 = (const float*)d_in[12];
    const float* cw2 = (const float*)d_in[13];
    const float* cb2 = (const float*)d_in[14];
    const float* nw  = (const float*)d_in[15];
    const float* nb  = (const float*)d_in[16];
    const float* num_target = (const float*)d_in[17];
    const int*   cat_target = (const int*)d_in[18];
    float* out = (float*)d_out;
    float* ws  = (float*)d_ws;

    size_t o = 0;
    float*    part = ws + o;                o += 4ull * 524288;   // 8 MB
    float*    Mf   = ws + o;                o += 1536;
    float*    beta = ws + o;                o += 256;
    ushort_t* zh   = (ushort_t*)(ws + o);   o += 32768;           // packed 256x256
    ushort_t* zl   = (ushort_t*)(ws + o);   o += 32768;
    ushort_t* r0h  = (ushort_t*)(ws + o);   o += 262144;          // packed 256x2048
    ushort_t* r0l  = (ushort_t*)(ws + o);   o += 262144;
    ushort_t* r1h  = (ushort_t*)(ws + o);   o += 262144;
    ushort_t* r1l  = (ushort_t*)(ws + o);   o += 262144;

    // 1. prep: z split+pack | head-weight fusion
    prep_small<<<dim3(166), 256, 0, stream>>>(
        z, cvw, cvb, cw0, cb0, cw1, cb1, cw2, cb2, nw, nb, zh, zl, Mf, beta);

    // 2. layer 0 (K=256, full-K): r0 = pack(relu(z@w0+b0))
    gemm_w2<1><<<dim3(32, 2, 1), 1024, 0, stream>>>(
        zh, zl, w0, b0, nullptr, r0h, r0l, 8, 8, 4);

    // 3-4. layer 1 (K=2048, splitK=4) + reduce -> r1 packed
    gemm_w2<0><<<dim3(32, 2, 4), 1024, 0, stream>>>(
        r0h, r0l, w1, nullptr, part, nullptr, nullptr, 64, 16, 8);
    reduce_pk<<<dim3(512), 256, 0, stream>>>(part, b1, r1h, r1l);

    // 5. layer 2 (K=2048, splitK=4) -> partials (reduced inline by heads)
    gemm_w2<0><<<dim3(32, 2, 4), 1024, 0, stream>>>(
        r1h, r1l, w2, nullptr, part, nullptr, nullptr, 64, 16, 8);

    // 6. heads (inline 4-partial reduce + bias + relu)
    heads_kernel<<<dim3(256), 256, 0, stream>>>(
        part, b2, Mf, beta, cat_target, num_target, out);
}

// Round 14
// 67.614 us; speedup vs baseline: 14.2870x; 1.0775x over previous
//
#include <hip/hip_runtime.h>
#include <hip/hip_fp16.h>
#include <math.h>

#define NN   256
#define LL   256
#define HH   512
#define MLPHv 2048
#define INCv 8
#define NCOLS 150

typedef _Float16 f16x8 __attribute__((ext_vector_type(8)));
typedef float    f32x4 __attribute__((ext_vector_type(4)));
typedef unsigned short ushort_t;

union u4f16 { uint4 u; f16x8 v; };

// ---------------------------------------------------------------------------
// fp32 -> fp16 hi/lo split:  a ≈ hi + lo/4096, |residual| <= 2^-22 |a|.
// ---------------------------------------------------------------------------
__device__ __forceinline__ void split1(float f, ushort_t& h, ushort_t& l)
{
    __half hh = __float2half_rn(f);
    h = __half_as_ushort(hh);
    l = __half_as_ushort(__float2half_rn((f - __half2float(hh)) * 4096.f));
}

__device__ __forceinline__ void pack8(const float* fv, uint4& hv, uint4& lv)
{
    ushort_t h[8], l[8];
#pragma unroll
    for (int j = 0; j < 8; ++j) split1(fv[j], h[j], l[j]);
    hv.x = (unsigned)h[0] | ((unsigned)h[1] << 16);
    hv.y = (unsigned)h[2] | ((unsigned)h[3] << 16);
    hv.z = (unsigned)h[4] | ((unsigned)h[5] << 16);
    hv.w = (unsigned)h[6] | ((unsigned)h[7] << 16);
    lv.x = (unsigned)l[0] | ((unsigned)l[1] << 16);
    lv.y = (unsigned)l[2] | ((unsigned)l[3] << 16);
    lv.z = (unsigned)l[4] | ((unsigned)l[5] << 16);
    lv.w = (unsigned)l[6] | ((unsigned)l[7] << 16);
}

// async global->LDS 16B per lane (linear dest: wave-uniform base + lane*16).
typedef __attribute__((address_space(3))) unsigned int lds_u32;
typedef __attribute__((address_space(1))) const unsigned int glb_u32;
__device__ __forceinline__ void gl_lds16(const ushort_t* g, ushort_t* l)
{
    __builtin_amdgcn_global_load_lds((glb_u32*)g, (lds_u32*)l, 16, 0, 0);
}
__device__ __forceinline__ void gl_lds16f(const float* g, float* l)
{
    __builtin_amdgcn_global_load_lds((glb_u32*)g, (lds_u32*)l, 16, 0, 0);
}

// Fragment-linear packing (R10-13 proven): X[row][k] lives at
// ((g*KS32 + ks)*64 + lane)*8 + j,  g=row>>4, ks=k>>5,
// lane=(row&15)+16*((k>>3)&3), j=k&7.

// ---------------------------------------------------------------------------
// prep_small: bid<16 -> z split+pack; else -> fused head weights (150 cols).
// ---------------------------------------------------------------------------
__global__ __launch_bounds__(256) void prep_small(
    const float* __restrict__ z,
    const float* __restrict__ cvw, const float* __restrict__ cvb,
    const float* __restrict__ cw0, const float* __restrict__ cb0,
    const float* __restrict__ cw1, const float* __restrict__ cb1,
    const float* __restrict__ cw2, const float* __restrict__ cb2,
    const float* __restrict__ nw,  const float* __restrict__ nbv,
    ushort_t* __restrict__ zh, ushort_t* __restrict__ zl,
    float* __restrict__ Mf, float* __restrict__ beta)
{
    const int bid = blockIdx.x;
    const int tid = threadIdx.x;
    if (bid < 16) {
        const int idx = bid * 256 + tid;            // 0..4095
        const int r = idx >> 4, kq = idx & 15;
        const float* p = z + (size_t)r * 256 + kq * 16;
        float fv[16];
#pragma unroll
        for (int q = 0; q < 4; ++q) {
            float4 v = *(const float4*)(p + q * 4);
            fv[q * 4 + 0] = v.x; fv[q * 4 + 1] = v.y;
            fv[q * 4 + 2] = v.z; fv[q * 4 + 3] = v.w;
        }
        const int gm = r >> 4, l16 = r & 15;
#pragma unroll
        for (int o = 0; o < 2; ++o) {
            uint4 hv, lv;
            pack8(&fv[o * 8], hv, lv);
            const int koct = kq * 2 + o;
            const int ks = koct >> 2, koct3 = koct & 3;
            const size_t off = ((size_t)(gm * 8 + ks) * 64 + l16 + (koct3 << 4)) * 8;
            *(uint4*)&zh[off] = hv;
            *(uint4*)&zl[off] = lv;
        }
    } else {
        const int k = bid - 16;
        const float* W; const float* B; int off, card;
        if (k < 4)        { W = cw0; B = cb0; off = 0;   card = 4;   }
        else if (k < 20)  { W = cw1; B = cb1; off = 4;   card = 16;  }
        else if (k < 148) { W = cw2; B = cb2; off = 20;  card = 128; }
        else              { W = nw;  B = nbv; off = 148; card = 2;   }
        const int kc = k - off;
        float part[INCv + 1];
#pragma unroll
        for (int c = 0; c <= INCv; ++c) part[c] = 0.f;
#pragma unroll
        for (int it = 0; it < 2; ++it) {
            const int h = tid + it * 256;
            const float wv = W[h * card + kc];
#pragma unroll
            for (int c = 0; c < INCv; ++c) part[c] += cvw[h * INCv + c] * wv;
            part[INCv] += cvb[h] * wv;
        }
        __shared__ float red[INCv + 1][4];
        const int lane = tid & 63, wave = tid >> 6;
#pragma unroll
        for (int c = 0; c <= INCv; ++c) {
            float v = part[c];
#pragma unroll
            for (int o = 32; o >= 1; o >>= 1) v += __shfl_down(v, o, 64);
            if (lane == 0) red[c][wave] = v;
        }
        __syncthreads();
        if (tid <= INCv) {
            const float s = red[tid][0] + red[tid][1] + red[tid][2] + red[tid][3];
            if (tid < INCv) Mf[tid * NCOLS + k] = s;
            else            beta[k] = s + B[kc];
        }
    }
}

// ---------------------------------------------------------------------------
// 512-thread MFMA GEMM, BM=64, BN=64, BK=64/step, 2 blocks/CU (LDS ~65KB).
// A = packed fp16 pairs (DMA).  W = raw fp32 rows (DMA into padded LDS),
// converted REGISTER-DIRECT per wave (each wave converts exactly the W
// fragment it consumes; 2x benign duplication; bank-2-way-free reads) --
// no sWh/sWl LDS, no third barrier.
// Step: STAGE(t+1) [4 DMA/wave] -> vmcnt(4) -> barrier -> {reg-convert W,
// ds_read A, MFMA} -> barrier.  Waves 2wr x 4wc, wave tile 32x16.
// acc = ah*bh + (ah*bl + al*bh)/4096.
// OUT=0: fp32 partial at part + bz*524288.
// OUT=1: bias+relu+split PACKED to oH/oL (next layer's A, KS32_next=64).
// ---------------------------------------------------------------------------
template <int OUT>
__global__ __launch_bounds__(512, 2) void gemm_v3(
    const ushort_t* __restrict__ Ah, const ushort_t* __restrict__ Al,
    const float* __restrict__ W, const float* __restrict__ bias,
    float* __restrict__ part, ushort_t* __restrict__ oH, ushort_t* __restrict__ oL,
    int KS32, int kchunk32, int steps)
{
    __shared__ ushort_t sAh[2][4096];   // packed A hi: 8 runs x 512
    __shared__ ushort_t sAl[2][4096];   // packed A lo
    __shared__ float    sWf[2][4160];   // raw fp32 W: 16 issues x 260 (pad 4)

    const int tid  = threadIdx.x;
    const int lane = tid & 63, w = tid >> 6;        // 8 waves
    const int wr   = w >> 2, wc = w & 3;            // 2 x 4 wave grid
    const int bx   = blockIdx.x, by = blockIdx.y, bz = blockIdx.z;
    const int bn   = bx * 64;
    const int kb0  = bz * kchunk32;

    f32x4 accH[2], accC[2];
#pragma unroll
    for (int r = 0; r < 2; ++r) {
        accH[r] = (f32x4){0.f, 0.f, 0.f, 0.f};
        accC[r] = (f32x4){0.f, 0.f, 0.f, 0.f};
    }

    auto STAGE = [&](int ts, int b) {
        const int kb = kb0 + ts * 2;
        // A: wave w stages run w (g = w>>1, ks = w&1), both planes
        const int g = w >> 1, ks = w & 1;
        const size_t fA = ((size_t)(by * 4 + g) * KS32 + kb + ks) * 512 + lane * 8;
        gl_lds16(Ah + fA, &sAh[b][w * 512]);
        gl_lds16(Al + fA, &sAl[b][w * 512]);
        // W fp32: wave w stages issues w*2, w*2+1 (each 4 k-rows x 64 cols)
        const int k0 = kb * 32;
#pragma unroll
        for (int ii = 0; ii < 2; ++ii) {
            const int i = w * 2 + ii;
            const float* src = W + (size_t)(k0 + i * 4 + (lane >> 4)) * 2048 + bn + (lane & 15) * 4;
            gl_lds16f(src, &sWf[b][i * 260]);
        }
    };

    STAGE(0, 0);
    for (int t = 0; t < steps; ++t) {
        const int cur = t & 1;
        if (t + 1 < steps) {
            STAGE(t + 1, cur ^ 1);
            asm volatile("s_waitcnt vmcnt(4)" ::: "memory");  // step t landed; t+1 in flight
        } else {
            asm volatile("s_waitcnt vmcnt(0)" ::: "memory");
        }
        __builtin_amdgcn_s_barrier();
        asm volatile("" ::: "memory");

        // ---- register-direct W convert for this wave's n-frag (col16, koct) ----
        f16x8 bH[2], bL[2];
#pragma unroll
        for (int ks = 0; ks < 2; ++ks) {
            const int col  = wc * 16 + (lane & 15);
            const int koct = lane >> 4;              // k-octet within ks-half
            float fv[8];
#pragma unroll
            for (int j = 0; j < 8; ++j) {
                const int i = ks * 8 + koct * 2 + (j >> 2);
                fv[j] = sWf[cur][i * 260 + (j & 3) * 64 + col];
            }
            u4f16 hv, lv;
            pack8(fv, hv.u, lv.u);
            bH[ks] = hv.v;
            bL[ks] = lv.v;
        }

        // ---- A frags + MFMA ----
#pragma unroll
        for (int ks = 0; ks < 2; ++ks) {
            f16x8 aH[2], aL[2];
#pragma unroll
            for (int r = 0; r < 2; ++r) {
                const int off = (((wr * 2 + r) * 2 + ks) * 64 + lane) * 8;
                aH[r] = *(const f16x8*)&sAh[cur][off];
                aL[r] = *(const f16x8*)&sAl[cur][off];
            }
#pragma unroll
            for (int r = 0; r < 2; ++r) {
                accH[r] = __builtin_amdgcn_mfma_f32_16x16x32_f16(aH[r], bH[ks], accH[r], 0, 0, 0);
                accC[r] = __builtin_amdgcn_mfma_f32_16x16x32_f16(aH[r], bL[ks], accC[r], 0, 0, 0);
                accC[r] = __builtin_amdgcn_mfma_f32_16x16x32_f16(aL[r], bH[ks], accC[r], 0, 0, 0);
            }
        }
        __builtin_amdgcn_s_barrier();   // reads of buf[cur] done before re-stage
        asm volatile("" ::: "memory");
    }

    const float inv = 1.f / 4096.f;
#pragma unroll
    for (int r = 0; r < 2; ++r) {
        const int row0 = by * 64 + (wr * 2 + r) * 16 + ((lane >> 4) << 2);
        const int col  = bn + wc * 16 + (lane & 15);
        if (OUT == 0) {
            float* po = part + (size_t)bz * 524288;
#pragma unroll
            for (int e = 0; e < 4; ++e)
                po[(size_t)(row0 + e) * 2048 + col] = accH[r][e] + accC[r][e] * inv;
        } else {
            const float vb = bias[col];
            const int gm = by * 4 + wr * 2 + r;
            const int ks = col >> 5, koct3 = (col >> 3) & 3, j = col & 7;
            const size_t fb = ((size_t)(gm * 64 + ks) * 64) * 8 + (koct3 << 4) * 8 + j;
#pragma unroll
            for (int e = 0; e < 4; ++e) {
                const float v = fmaxf(accH[r][e] + accC[r][e] * inv + vb, 0.f);
                ushort_t h, l;
                split1(v, h, l);
                const int l16 = ((lane >> 4) << 2) + e;
                oH[fb + (size_t)l16 * 8] = h;
                oL[fb + (size_t)l16 * 8] = l;
            }
        }
    }
}

// ---------------------------------------------------------------------------
// Reduce 4 partials + bias + relu -> packed fp16 pairs (next layer's A).
// ---------------------------------------------------------------------------
__global__ __launch_bounds__(256) void reduce_pk(
    const float* __restrict__ part, const float* __restrict__ bias,
    ushort_t* __restrict__ oH, ushort_t* __restrict__ oL)
{
    const int b  = blockIdx.x;        // 512 blocks
    const int ct = b & 15, rg = b >> 4;
    const int e  = threadIdx.x * 4;
    const int row = rg * 8 + (e >> 7);
    const int col = ct * 128 + (e & 127);
    const size_t idx = (size_t)row * 2048 + col;
    float4 s = *(const float4*)&bias[col];
#pragma unroll
    for (int k = 0; k < 4; ++k) {
        const float4 p = *(const float4*)&part[(size_t)k * 524288 + idx];
        s.x += p.x; s.y += p.y; s.z += p.z; s.w += p.w;
    }
    s.x = fmaxf(s.x, 0.f); s.y = fmaxf(s.y, 0.f);
    s.z = fmaxf(s.z, 0.f); s.w = fmaxf(s.w, 0.f);
    ushort_t h[4], l[4];
    split1(s.x, h[0], l[0]); split1(s.y, h[1], l[1]);
    split1(s.z, h[2], l[2]); split1(s.w, h[3], l[3]);
    const int gm = row >> 4, l16 = row & 15;
    const int ks = col >> 5, koct3 = (col >> 3) & 3, j = col & 7;
    const size_t off = ((size_t)(gm * 64 + ks) * 64 + l16 + (koct3 << 4)) * 8 + j;
    ushort4 hv = {h[0], h[1], h[2], h[3]};
    ushort4 lv = {l[0], l[1], l[2], l[3]};
    *(ushort4*)&oH[off] = hv;
    *(ushort4*)&oL[off] = lv;
}

// ---------------------------------------------------------------------------
// Heads with INLINE layer-2 reduction (R11-13 proven).
// ---------------------------------------------------------------------------
__global__ __launch_bounds__(256) void heads_kernel(
    const float* __restrict__ part, const float* __restrict__ b2,
    const float* __restrict__ Mf, const float* __restrict__ beta,
    const int* __restrict__ cat_target, const float* __restrict__ num_target,
    float* __restrict__ out)
{
    const int bx  = blockIdx.x;
    const int tid = threadIdx.x;
    __shared__ float Ms[INCv][128];
    __shared__ float Bsh[128];
    if (bx < 96) {
        const int g = bx >> 5;
        const int card = (g == 0) ? 4 : (g == 1) ? 16 : 128;
        const int off  = (g == 0) ? 0 : (g == 1) ? 4  : 20;
        for (int i = tid; i < card * INCv; i += 256) {
            int c = i / card, k = i % card;
            Ms[c][k] = Mf[c * NCOLS + off + k];
        }
        for (int i = tid; i < card; i += 256) Bsh[i] = beta[off + i];
        __syncthreads();

        const int idx = (bx & 31) * 256 + tid;
        const int n = idx >> 5, j = idx & 31;
        const int ci = g * 32 + j;
        const int l  = ci * 2;
        float rv[INCv];
#pragma unroll
        for (int c = 0; c < INCv; ++c) {
            const size_t e = (size_t)n * MLPHv + c * LL + l;
            float s = b2[c * LL + l];
#pragma unroll
            for (int k = 0; k < 4; ++k) s += part[(size_t)k * 524288 + e];
            rv[c] = fmaxf(s, 0.f);
        }

        float mx = -1e30f; int arg = 0;
        for (int k = 0; k < card; ++k) {
            float s = Bsh[k];
#pragma unroll
            for (int c = 0; c < INCv; ++c) s += rv[c] * Ms[c][k];
            if (s > mx) { mx = s; arg = k; }
        }
        const int tg = cat_target[n * 96 + ci];
        float sum = 0.f, stg = 0.f;
        for (int k = 0; k < card; ++k) {
            float s = Bsh[k];
#pragma unroll
            for (int c = 0; c < INCv; ++c) s += rv[c] * Ms[c][k];
            sum += expf(s - mx);
            if (k == tg) stg = s;
        }
        const float lse = mx + logf(sum);
        out[NN * LL * 3 + n * 96 + ci] = lse - stg;
        float* u = out + (size_t)(n * LL + l) * 3;
        u[0] = (float)arg; u[1] = 0.f; u[2] = 0.f;
    } else {
        const int idx = (bx - 96) * 256 + tid;  // 0..40959
        const int n = idx / 160, ni = idx % 160;
        const int l = (ni < 96) ? (2 * ni + 1) : (96 + ni);
        float rv[INCv];
#pragma unroll
        for (int c = 0; c < INCv; ++c) {
            const size_t e = (size_t)n * MLPHv + c * LL + l;
            float s = b2[c * LL + l];
#pragma unroll
            for (int k = 0; k < 4; ++k) s += part[(size_t)k * 524288 + e];
            rv[c] = fmaxf(s, 0.f);
        }
        float p0 = beta[148], p1 = beta[149];
#pragma unroll
        for (int c = 0; c < INCv; ++c) {
            p0 += rv[c] * Mf[c * NCOLS + 148];
            p1 += rv[c] * Mf[c * NCOLS + 149];
        }
        const float mu = 1.f / (1.f + expf(-p0));
        const float sp = (p1 > 20.f) ? p1 : log1pf(expf(p1));
        const float s  = sp + 1e-4f;
        const float hb = 1.f / 198.f;
        const float t  = num_target[n * 160 + ni];
        const float cp = 1.f / (1.f + expf(-((t + hb - mu) / s)));
        const float cm = 1.f / (1.f + expf(-((t - hb - mu) / s)));
        const float prob = (t < hb) ? cp : ((t > 1.f - hb) ? (1.f - cm) : (cp - cm));
        out[NN * LL * 3 + NN * 96 + n * 160 + ni] = -logf(fmaxf(prob, 1e-7f));
        float* u = out + (size_t)(n * LL + l) * 3;
        u[0] = 0.f; u[1] = rintf(mu * 99.f) / 99.f; u[2] = 0.f;
    }
}

// ---------------------------------------------------------------------------
extern "C" void kernel_launch(void* const* d_in, const int* in_sizes, int n_in,
                              void* d_out, int out_size, void* d_ws, size_t ws_size,
                              hipStream_t stream)
{
    const float* z   = (const float*)d_in[0];
    const float* w0  = (const float*)d_in[1];
    const float* b0  = (const float*)d_in[2];
    const float* w1  = (const float*)d_in[3];
    const float* b1  = (const float*)d_in[4];
    const float* w2  = (const float*)d_in[5];
    const float* b2  = (const float*)d_in[6];
    const float* cvw = (const float*)d_in[7];
    const float* cvb = (const float*)d_in[8];
    const float* cw0 = (const float*)d_in[9];
    const float* cb0 = (const float*)d_in[10];
    const float* cw1 = (const float*)d_in[11];
    const float* cb1 = (const float*)d_in[12];
    const float* cw2 = (const float*)d_in[13];
    const float* cb2 = (const float*)d_in[14];
    const float* nw  = (const float*)d_in[15];
    const float* nb  = (const float*)d_in[16];
    const float* num_target = (const float*)d_in[17];
    const int*   cat_target = (const int*)d_in[18];
    float* out = (float*)d_out;
    float* ws  = (float*)d_ws;

    size_t o = 0;
    float*    part = ws + o;                o += 4ull * 524288;   // 8 MB
    float*    Mf   = ws + o;                o += 1536;
    float*    beta = ws + o;                o += 256;
    ushort_t* zh   = (ushort_t*)(ws + o);   o += 32768;           // packed 256x256
    ushort_t* zl   = (ushort_t*)(ws + o);   o += 32768;
    ushort_t* r0h  = (ushort_t*)(ws + o);   o += 262144;          // packed 256x2048
    ushort_t* r0l  = (ushort_t*)(ws + o);   o += 262144;
    ushort_t* r1h  = (ushort_t*)(ws + o);   o += 262144;
    ushort_t* r1l  = (ushort_t*)(ws + o);   o += 262144;

    // 1. prep: z split+pack | head-weight fusion
    prep_small<<<dim3(166), 256, 0, stream>>>(
        z, cvw, cvb, cw0, cb0, cw1, cb1, cw2, cb2, nw, nb, zh, zl, Mf, beta);

    // 2. layer 0 (K=256, full-K): r0 = pack(relu(z@w0+b0))
    gemm_v3<1><<<dim3(32, 4, 1), 512, 0, stream>>>(
        zh, zl, w0, b0, nullptr, r0h, r0l, 8, 8, 4);

    // 3-4. layer 1 (K=2048, splitK=4) + reduce -> r1 packed
    gemm_v3<0><<<dim3(32, 4, 4), 512, 0, stream>>>(
        r0h, r0l, w1, nullptr, part, nullptr, nullptr, 64, 16, 8);
    reduce_pk<<<dim3(512), 256, 0, stream>>>(part, b1, r1h, r1l);

    // 5. layer 2 (K=2048, splitK=4) -> partials (reduced inline by heads)
    gemm_v3<0><<<dim3(32, 4, 4), 512, 0, stream>>>(
        r1h, r1l, w2, nullptr, part, nullptr, nullptr, 64, 16, 8);

    // 6. heads (inline 4-partial reduce + bias + relu)
    heads_kernel<<<dim3(256), 256, 0, stream>>>(
        part, b2, Mf, beta, cat_target, num_target, out);
}